// Round 3
// baseline (5801.495 us; speedup 1.0000x reference)
//
#include <hip/hip_runtime.h>
#include <math.h>

#define B_ 16
#define T_ 128
#define S_ 256
#define H_ 512
#define M_ 512
#define V_ 32000

// ---------------- embedding gather ----------------
__global__ __launch_bounds__(128) void k_gather(const int* __restrict__ tgt,
    const float* __restrict__ embed, float* __restrict__ x)
{
  const int row = blockIdx.x;          // b*T+t
  const int v = tgt[row];
  const float4* src = (const float4*)(embed + (size_t)v * H_);
  float4* dst = (float4*)(x + (size_t)row * H_);
  dst[threadIdx.x] = src[threadIdx.x];
}

// ---------------- f32 NT GEMM + bias: C[M][N] = A[M][512] * B[N][512]^T + bias[N]
__global__ __launch_bounds__(256) void k_gemm_nt_bias(const float* __restrict__ A,
    const float* __restrict__ Bm, const float* __restrict__ bias,
    float* __restrict__ C, int N)
{
  __shared__ float As[64][33];
  __shared__ float Bs[64][33];
  const int tid = threadIdx.x;
  const int tm = tid >> 4, tn = tid & 15;
  const float* Ab = A  + (size_t)blockIdx.y * 64 * 512;
  const float* Bb = Bm + (size_t)blockIdx.x * 64 * 512;
  float acc00=0.f,acc01=0.f,acc02=0.f,acc03=0.f;
  float acc10=0.f,acc11=0.f,acc12=0.f,acc13=0.f;
  float acc20=0.f,acc21=0.f,acc22=0.f,acc23=0.f;
  float acc30=0.f,acc31=0.f,acc32=0.f,acc33=0.f;
  for (int k0 = 0; k0 < 512; k0 += 32) {
#pragma unroll
    for (int i = 0; i < 8; ++i) {
      int v = tid + i * 256;
      int row = v >> 5, col = v & 31;
      As[row][col] = Ab[(size_t)row * 512 + k0 + col];
      Bs[row][col] = Bb[(size_t)row * 512 + k0 + col];
    }
    __syncthreads();
#pragma unroll
    for (int kk = 0; kk < 32; ++kk) {
      float a0 = As[tm*4+0][kk], a1 = As[tm*4+1][kk];
      float a2 = As[tm*4+2][kk], a3 = As[tm*4+3][kk];
      float b0 = Bs[tn*4+0][kk], b1 = Bs[tn*4+1][kk];
      float b2 = Bs[tn*4+2][kk], b3 = Bs[tn*4+3][kk];
      acc00 += a0*b0; acc01 += a0*b1; acc02 += a0*b2; acc03 += a0*b3;
      acc10 += a1*b0; acc11 += a1*b1; acc12 += a1*b2; acc13 += a1*b3;
      acc20 += a2*b0; acc21 += a2*b1; acc22 += a2*b2; acc23 += a2*b3;
      acc30 += a3*b0; acc31 += a3*b1; acc32 += a3*b2; acc33 += a3*b3;
    }
    __syncthreads();
  }
  const int mbase = blockIdx.y*64 + tm*4;
  const int nbase = blockIdx.x*64 + tn*4;
  float bj0 = bias[nbase+0], bj1 = bias[nbase+1], bj2 = bias[nbase+2], bj3 = bias[nbase+3];
  float* Cr0 = C + (size_t)(mbase+0)*N + nbase;
  float* Cr1 = C + (size_t)(mbase+1)*N + nbase;
  float* Cr2 = C + (size_t)(mbase+2)*N + nbase;
  float* Cr3 = C + (size_t)(mbase+3)*N + nbase;
  Cr0[0]=acc00+bj0; Cr0[1]=acc01+bj1; Cr0[2]=acc02+bj2; Cr0[3]=acc03+bj3;
  Cr1[0]=acc10+bj0; Cr1[1]=acc11+bj1; Cr1[2]=acc12+bj2; Cr1[3]=acc13+bj3;
  Cr2[0]=acc20+bj0; Cr2[1]=acc21+bj1; Cr2[2]=acc22+bj2; Cr2[3]=acc23+bj3;
  Cr3[0]=acc30+bj0; Cr3[1]=acc31+bj1; Cr3[2]=acc32+bj2; Cr3[3]=acc33+bj3;
}

// ---------------- fused 2-layer GRU, fence-free pipeline ----------------
// 128 WGs x 512 threads. WGs [0,64): layer 0; [64,128): layer 1 (one step behind).
// Communication: relaxed agent atomic stores (write-through, sc1) + per-WG flags.
// No acquire/release fences -> no buffer_inv / buffer_wbl2 on the critical path.
__global__ __launch_bounds__(512) void k_gru2(
    const float* __restrict__ xg0,
    const float* __restrict__ Whh0, const float* __restrict__ bhh0,
    const float* __restrict__ Wih1, const float* __restrict__ bih1,
    const float* __restrict__ Whh1, const float* __restrict__ bhh1,
    const float* __restrict__ hidden,
    float* __restrict__ out0, float* __restrict__ y1, float* __restrict__ hn,
    unsigned int* __restrict__ fA, unsigned int* __restrict__ fB)
{
  __shared__ float Wl[24][516];       // this WG's 24 W_hh rows (3 gates x 8 dims)
  __shared__ float hlds[2][16*516];   // staged h_prev [0]; staged out0[t] [1] (layer 1)
  __shared__ float ps[4][6][128];     // matvec partials [k-quarter][gate][b*8+dl]
  const int bid = blockIdx.x;
  const bool isB = bid >= 64;
  const int wg = isB ? bid - 64 : bid;
  const int dbase = wg * 8;
  const int lt = threadIdx.x;
  const float* Whh = isB ? Whh1 : Whh0;
  for (int r = 0; r < 24; ++r) {
    const int gate = r >> 3, dl2 = r & 7;
    Wl[r][lt] = Whh[(size_t)(gate * 512 + dbase + dl2) * 512 + lt];
  }
  const int kq  = lt >> 7;            // k-quarter 0..3
  const int rem = lt & 127;
  const int b   = rem >> 3;           // batch
  const int dl  = rem & 7;            // local dim
  const int k0  = kq << 7;
  const int sb  = lt >> 5;            // staging batch
  const int sc  = lt & 31;            // staging chunk lane
  float* ybuf = isB ? y1 : out0;
  const float* h0g = hidden + (isB ? 8192 : 0);
  const float* wrp = &Wl[dl][k0];
  const float* wzp = &Wl[8 + dl][k0];
  const float* wnp = &Wl[16 + dl][k0];
  const float* urp = Wih1 + (size_t)(       dbase + dl) * 512 + k0;
  const float* uzp = Wih1 + (size_t)( 512 + dbase + dl) * 512 + k0;
  const float* unp = Wih1 + (size_t)(1024 + dbase + dl) * 512 + k0;
  unsigned int* fMine = isB ? fB : fA;
  // final-phase per-thread constants (threads lt<128)
  const int bb = lt >> 3;
  const int dg = dbase + (lt & 7);
  float hreg = 0.f, bhr = 0.f, bhz = 0.f, bhn = 0.f, bir = 0.f, biz = 0.f, bin_ = 0.f;
  if (lt < 128) {
    hreg = h0g[bb * 512 + dg];
    const float* bhh = isB ? bhh1 : bhh0;
    bhr = bhh[dg]; bhz = bhh[512 + dg]; bhn = bhh[1024 + dg];
    if (isB) { bir = bih1[dg]; biz = bih1[512 + dg]; bin_ = bih1[1024 + dg]; }
  }
  __syncthreads();

  for (int t = 0; t < T_; ++t) {
    // ---- wait on dependencies (wave 0 polls 64 per-WG flags in parallel) ----
    if (lt < 64) {
      unsigned v;
      if (isB) {
        do { v = __hip_atomic_load(&fA[t * 64 + lt], __ATOMIC_RELAXED, __HIP_MEMORY_SCOPE_AGENT); }
        while (!__all(v != 0u));
        if (t) {
          do { v = __hip_atomic_load(&fB[(t - 1) * 64 + lt], __ATOMIC_RELAXED, __HIP_MEMORY_SCOPE_AGENT); }
          while (!__all(v != 0u));
        }
      } else if (t) {
        do { v = __hip_atomic_load(&fA[(t - 1) * 64 + lt], __ATOMIC_RELAXED, __HIP_MEMORY_SCOPE_AGENT); }
        while (!__all(v != 0u));
      }
    }
    __syncthreads();

    // ---- stage h_prev (and out0[t] for layer 1) into LDS via coherent loads ----
    if (t) {
      float* hsrc = &ybuf[(size_t)(sb * T_ + t - 1) * 512];
#pragma unroll
      for (int j = 0; j < 16; ++j)
        hlds[0][sb * 516 + sc + j * 32] =
            __hip_atomic_load(&hsrc[sc + j * 32], __ATOMIC_RELAXED, __HIP_MEMORY_SCOPE_AGENT);
    } else {
#pragma unroll
      for (int j = 0; j < 16; ++j)
        hlds[0][sb * 516 + sc + j * 32] = h0g[sb * 512 + sc + j * 32];
    }
    if (isB) {
      float* osrc = &out0[(size_t)(sb * T_ + t) * 512];
#pragma unroll
      for (int j = 0; j < 16; ++j)
        hlds[1][sb * 516 + sc + j * 32] =
            __hip_atomic_load(&osrc[sc + j * 32], __ATOMIC_RELAXED, __HIP_MEMORY_SCOPE_AGENT);
    }
    __syncthreads();

    // ---- matvec from LDS ----
    float ar = 0.f, az = 0.f, an = 0.f, xr = 0.f, xz = 0.f, xn = 0.f;
    const float* hb = &hlds[0][b * 516 + k0];
    if (!isB) {
#pragma unroll
      for (int i = 0; i < 32; ++i) {
        float4 hv = *(const float4*)(hb + 4 * i);
        float4 wr = *(const float4*)(wrp + 4 * i);
        float4 wz = *(const float4*)(wzp + 4 * i);
        float4 wn = *(const float4*)(wnp + 4 * i);
        ar += hv.x*wr.x + hv.y*wr.y + hv.z*wr.z + hv.w*wr.w;
        az += hv.x*wz.x + hv.y*wz.y + hv.z*wz.z + hv.w*wz.w;
        an += hv.x*wn.x + hv.y*wn.y + hv.z*wn.z + hv.w*wn.w;
      }
    } else {
      const float* ob = &hlds[1][b * 516 + k0];
#pragma unroll
      for (int i = 0; i < 32; ++i) {
        float4 hv = *(const float4*)(hb + 4 * i);
        float4 ov = *(const float4*)(ob + 4 * i);
        float4 wr = *(const float4*)(wrp + 4 * i);
        float4 wz = *(const float4*)(wzp + 4 * i);
        float4 wn = *(const float4*)(wnp + 4 * i);
        float4 ur = *(const float4*)(urp + 4 * i);
        float4 uz = *(const float4*)(uzp + 4 * i);
        float4 un = *(const float4*)(unp + 4 * i);
        ar += hv.x*wr.x + hv.y*wr.y + hv.z*wr.z + hv.w*wr.w;
        az += hv.x*wz.x + hv.y*wz.y + hv.z*wz.z + hv.w*wz.w;
        an += hv.x*wn.x + hv.y*wn.y + hv.z*wn.z + hv.w*wn.w;
        xr += ov.x*ur.x + ov.y*ur.y + ov.z*ur.z + ov.w*ur.w;
        xz += ov.x*uz.x + ov.y*uz.y + ov.z*uz.z + ov.w*uz.w;
        xn += ov.x*un.x + ov.y*un.y + ov.z*un.z + ov.w*un.w;
      }
    }
    ps[kq][0][rem] = ar; ps[kq][1][rem] = az; ps[kq][2][rem] = an;
    if (isB) { ps[kq][3][rem] = xr; ps[kq][4][rem] = xz; ps[kq][5][rem] = xn; }
    __syncthreads();

    // ---- reduce + activations + state update (threads 0..127) ----
    if (lt < 128) {
      float ghr = ps[0][0][lt] + ps[1][0][lt] + ps[2][0][lt] + ps[3][0][lt] + bhr;
      float ghz = ps[0][1][lt] + ps[1][1][lt] + ps[2][1][lt] + ps[3][1][lt] + bhz;
      float ghn = ps[0][2][lt] + ps[1][2][lt] + ps[2][2][lt] + ps[3][2][lt] + bhn;
      float ixr, ixz, ixn;
      if (!isB) {
        const float* xrow = xg0 + (size_t)(bb * T_ + t) * 1536;
        ixr = xrow[dg]; ixz = xrow[512 + dg]; ixn = xrow[1024 + dg];
      } else {
        ixr = ps[0][3][lt] + ps[1][3][lt] + ps[2][3][lt] + ps[3][3][lt] + bir;
        ixz = ps[0][4][lt] + ps[1][4][lt] + ps[2][4][lt] + ps[3][4][lt] + biz;
        ixn = ps[0][5][lt] + ps[1][5][lt] + ps[2][5][lt] + ps[3][5][lt] + bin_;
      }
      float rr = 1.f / (1.f + expf(-(ixr + ghr)));
      float zz = 1.f / (1.f + expf(-(ixz + ghz)));
      float nn = tanhf(ixn + rr * ghn);
      float hnew = (1.f - zz) * nn + zz * hreg;
      hreg = hnew;
      __hip_atomic_store(&ybuf[(size_t)(bb * T_ + t) * 512 + dg], hnew,
                         __ATOMIC_RELAXED, __HIP_MEMORY_SCOPE_AGENT);
      if (t == T_ - 1) hn[(isB ? 8192 : 0) + bb * 512 + dg] = hnew;
    }
    __syncthreads();   // per-wave vmcnt(0) drain before barrier -> stores at coherent point
    if (lt == 0)
      __hip_atomic_store(&fMine[t * 64 + wg], 1u, __ATOMIC_RELAXED, __HIP_MEMORY_SCOPE_AGENT);
  }
}

// ---------------- attention: one WG per (b,t) row ----------------
__global__ __launch_bounds__(256) void k_attn(const float* __restrict__ y,
    const float* __restrict__ enc, float* __restrict__ aout)
{
  __shared__ float orow[512];
  __shared__ float wbuf[256];
  __shared__ float red[8];
  const int row = blockIdx.x;        // b*T+t
  const int b = row >> 7;
  const int lt = threadIdx.x;
  orow[lt]       = y[(size_t)row*512 + lt];
  orow[lt + 256] = y[(size_t)row*512 + lt + 256];
  __syncthreads();
  const float* er = enc + (size_t)(b*S_ + lt) * 512;
  float acc = 0.f;
  for (int k = 0; k < 512; k += 4) {
    float4 e = *(const float4*)(er + k);
    acc += orow[k]*e.x + orow[k+1]*e.y + orow[k+2]*e.z + orow[k+3]*e.w;
  }
  float m = acc;
#pragma unroll
  for (int off = 32; off > 0; off >>= 1) m = fmaxf(m, __shfl_down(m, off));
  if ((lt & 63) == 0) red[lt >> 6] = m;
  __syncthreads();
  float mx = fmaxf(fmaxf(red[0], red[1]), fmaxf(red[2], red[3]));
  float e = expf(acc - mx);
  wbuf[lt] = e;
  float s = e;
#pragma unroll
  for (int off = 32; off > 0; off >>= 1) s += __shfl_down(s, off);
  if ((lt & 63) == 0) red[4 + (lt >> 6)] = s;
  __syncthreads();
  const float inv = 1.f / (red[4] + red[5] + red[6] + red[7]);
  const int kk = lt * 2;
  float c0 = 0.f, c1 = 0.f;
  for (int s2 = 0; s2 < S_; ++s2) {
    float ws = wbuf[s2];
    float2 ev = *(const float2*)(enc + (size_t)(b*S_ + s2)*512 + kk);
    c0 += ws * ev.x; c1 += ws * ev.y;
  }
  aout[(size_t)row*512 + kk]     = orow[kk]     + c0 * inv;
  aout[(size_t)row*512 + kk + 1] = orow[kk + 1] + c1 * inv;
}

extern "C" void kernel_launch(void* const* d_in, const int* in_sizes, int n_in,
                              void* d_out, int out_size, void* d_ws, size_t ws_size,
                              hipStream_t stream)
{
  const int*   tgt    = (const int*)  d_in[0];
  const float* hidden = (const float*)d_in[1];
  const float* enc    = (const float*)d_in[2];
  const float* embed  = (const float*)d_in[3];
  const float* W_ih0  = (const float*)d_in[4];
  const float* W_hh0  = (const float*)d_in[5];
  const float* b_ih0  = (const float*)d_in[6];
  const float* b_hh0  = (const float*)d_in[7];
  const float* W_ih1  = (const float*)d_in[8];
  const float* W_hh1  = (const float*)d_in[9];
  const float* b_ih1  = (const float*)d_in[10];
  const float* b_hh1  = (const float*)d_in[11];
  const float* W_out  = (const float*)d_in[12];
  const float* b_out  = (const float*)d_in[13];
  float* out = (float*)d_out;

  float* ws   = (float*)d_ws;
  float* xbuf = ws;                          // 2048*512   (x, later attn_out)
  float* xg   = ws + 1048576;                // 2048*1536  (layer-0 input gates)
  float* out0 = xg + 3145728;                // 2048*512
  float* y1   = out0 + 1048576;              // 2048*512
  unsigned int* flags = (unsigned int*)(y1 + 1048576);   // 2 * 128 * 64 flags

  const size_t logitsN = (size_t)(B_*T_) * V_;   // 65,536,000
  float* hn = out + logitsN;
  float* cn = hn + 16384;

  hipMemsetAsync(flags, 0, 2 * T_ * 64 * sizeof(unsigned int), stream);
  hipMemsetAsync(cn, 0, (size_t)16384 * sizeof(float), stream);   // cn = zeros

  k_gather<<<dim3(B_*T_), dim3(128), 0, stream>>>(tgt, embed, xbuf);
  k_gemm_nt_bias<<<dim3(1536/64, (B_*T_)/64), dim3(256), 0, stream>>>(xbuf, W_ih0, b_ih0, xg, 1536);
  k_gru2<<<dim3(128), dim3(512), 0, stream>>>(xg, W_hh0, b_hh0, W_ih1, b_ih1, W_hh1, b_hh1,
                                              hidden, out0, y1, hn, flags, flags + T_ * 64);
  k_attn<<<dim3(B_*T_), dim3(256), 0, stream>>>(y1, enc, xbuf);
  k_gemm_nt_bias<<<dim3(V_/64, (B_*T_)/64), dim3(256), 0, stream>>>(xbuf, W_out, b_out, out, V_);
}

// Round 4
// 4139.048 us; speedup vs baseline: 1.4016x; 1.4016x over previous
//
#include <hip/hip_runtime.h>
#include <math.h>

#define B_ 16
#define T_ 128
#define S_ 256
#define H_ 512
#define M_ 512
#define V_ 32000

typedef __attribute__((ext_vector_type(8))) short short8v;
typedef __attribute__((ext_vector_type(4))) float float4v;

// ---------------- embedding gather ----------------
__global__ __launch_bounds__(128) void k_gather(const int* __restrict__ tgt,
    const float* __restrict__ embed, float* __restrict__ x)
{
  const int row = blockIdx.x;          // b*T+t
  const int v = tgt[row];
  const float4* src = (const float4*)(embed + (size_t)v * H_);
  float4* dst = (float4*)(x + (size_t)row * H_);
  dst[threadIdx.x] = src[threadIdx.x];
}

// ---------------- f32 NT GEMM + bias (used for xg0 only) ----------------
__global__ __launch_bounds__(256) void k_gemm_nt_bias(const float* __restrict__ A,
    const float* __restrict__ Bm, const float* __restrict__ bias,
    float* __restrict__ C, int N)
{
  __shared__ float As[64][33];
  __shared__ float Bs[64][33];
  const int tid = threadIdx.x;
  const int tm = tid >> 4, tn = tid & 15;
  const float* Ab = A  + (size_t)blockIdx.y * 64 * 512;
  const float* Bb = Bm + (size_t)blockIdx.x * 64 * 512;
  float acc00=0.f,acc01=0.f,acc02=0.f,acc03=0.f;
  float acc10=0.f,acc11=0.f,acc12=0.f,acc13=0.f;
  float acc20=0.f,acc21=0.f,acc22=0.f,acc23=0.f;
  float acc30=0.f,acc31=0.f,acc32=0.f,acc33=0.f;
  for (int k0 = 0; k0 < 512; k0 += 32) {
#pragma unroll
    for (int i = 0; i < 8; ++i) {
      int v = tid + i * 256;
      int row = v >> 5, col = v & 31;
      As[row][col] = Ab[(size_t)row * 512 + k0 + col];
      Bs[row][col] = Bb[(size_t)row * 512 + k0 + col];
    }
    __syncthreads();
#pragma unroll
    for (int kk = 0; kk < 32; ++kk) {
      float a0 = As[tm*4+0][kk], a1 = As[tm*4+1][kk];
      float a2 = As[tm*4+2][kk], a3 = As[tm*4+3][kk];
      float b0 = Bs[tn*4+0][kk], b1 = Bs[tn*4+1][kk];
      float b2 = Bs[tn*4+2][kk], b3 = Bs[tn*4+3][kk];
      acc00 += a0*b0; acc01 += a0*b1; acc02 += a0*b2; acc03 += a0*b3;
      acc10 += a1*b0; acc11 += a1*b1; acc12 += a1*b2; acc13 += a1*b3;
      acc20 += a2*b0; acc21 += a2*b1; acc22 += a2*b2; acc23 += a2*b3;
      acc30 += a3*b0; acc31 += a3*b1; acc32 += a3*b2; acc33 += a3*b3;
    }
    __syncthreads();
  }
  const int mbase = blockIdx.y*64 + tm*4;
  const int nbase = blockIdx.x*64 + tn*4;
  float bj0 = bias[nbase+0], bj1 = bias[nbase+1], bj2 = bias[nbase+2], bj3 = bias[nbase+3];
  float* Cr0 = C + (size_t)(mbase+0)*N + nbase;
  float* Cr1 = C + (size_t)(mbase+1)*N + nbase;
  float* Cr2 = C + (size_t)(mbase+2)*N + nbase;
  float* Cr3 = C + (size_t)(mbase+3)*N + nbase;
  Cr0[0]=acc00+bj0; Cr0[1]=acc01+bj1; Cr0[2]=acc02+bj2; Cr0[3]=acc03+bj3;
  Cr1[0]=acc10+bj0; Cr1[1]=acc11+bj1; Cr1[2]=acc12+bj2; Cr1[3]=acc13+bj3;
  Cr2[0]=acc20+bj0; Cr2[1]=acc21+bj1; Cr2[2]=acc22+bj2; Cr2[3]=acc23+bj3;
  Cr3[0]=acc30+bj0; Cr3[1]=acc31+bj1; Cr3[2]=acc32+bj2; Cr3[3]=acc33+bj3;
}

// ---------------- one GRU timestep (both layers, pipelined) ----------------
// Dispatch t: WGs [0,64) compute layer-0 step t; WGs [64,128) compute layer-1
// step t-1 (its input row out0[t-1] was produced by the previous dispatch).
// Kernel boundary = device-wide sync; all loads/stores plain cached.
__global__ __launch_bounds__(512) void k_step(
    const float* __restrict__ xg0,
    const float* __restrict__ Whh0, const float* __restrict__ bhh0,
    const float* __restrict__ Wih1, const float* __restrict__ bih1,
    const float* __restrict__ Whh1, const float* __restrict__ bhh1,
    const float* __restrict__ hidden,
    float* __restrict__ out0, float* __restrict__ y1, float* __restrict__ hn,
    int t)
{
  const int bid = blockIdx.x;
  const bool isB = bid >= 64;
  const int ts = isB ? t - 1 : t;
  if (ts < 0 || ts >= T_) return;

  __shared__ float Wl[24][516];
  __shared__ float ps[4][6][128];
  const int wg = bid & 63;
  const int dbase = wg * 8;
  const int lt = threadIdx.x;
  const float* Whh = isB ? Whh1 : Whh0;
  for (int i = lt; i < 24 * 512; i += 512) {
    const int r = i >> 9, k = i & 511;
    Wl[r][k] = Whh[(size_t)((r >> 3) * 512 + dbase + (r & 7)) * 512 + k];
  }
  __syncthreads();

  const int kq  = lt >> 7;
  const int rem = lt & 127;
  const int b   = rem >> 3;
  const int dl  = rem & 7;
  const int k0  = kq << 7;
  float* ybuf = isB ? y1 : out0;
  const float* h0g = hidden + (isB ? 8192 : 0);
  const float* hsrc = ts ? (ybuf + (size_t)(b * T_ + ts - 1) * 512)
                         : (h0g + b * 512);
  const float* hb = hsrc + k0;
  const float* wrp = &Wl[dl][k0];
  const float* wzp = &Wl[8 + dl][k0];
  const float* wnp = &Wl[16 + dl][k0];

  float ar = 0.f, az = 0.f, an = 0.f, xr = 0.f, xz = 0.f, xn = 0.f;
  if (!isB) {
#pragma unroll 8
    for (int i = 0; i < 32; ++i) {
      float4 hv = *(const float4*)(hb + 4 * i);
      float4 wr = *(const float4*)(wrp + 4 * i);
      float4 wz = *(const float4*)(wzp + 4 * i);
      float4 wn = *(const float4*)(wnp + 4 * i);
      ar += hv.x*wr.x + hv.y*wr.y + hv.z*wr.z + hv.w*wr.w;
      az += hv.x*wz.x + hv.y*wz.y + hv.z*wz.z + hv.w*wz.w;
      an += hv.x*wn.x + hv.y*wn.y + hv.z*wn.z + hv.w*wn.w;
    }
  } else {
    const float* ob  = out0 + (size_t)(b * T_ + ts) * 512 + k0;
    const float* urp = Wih1 + (size_t)(       dbase + dl) * 512 + k0;
    const float* uzp = Wih1 + (size_t)( 512 + dbase + dl) * 512 + k0;
    const float* unp = Wih1 + (size_t)(1024 + dbase + dl) * 512 + k0;
#pragma unroll 4
    for (int i = 0; i < 32; ++i) {
      float4 hv = *(const float4*)(hb + 4 * i);
      float4 ov = *(const float4*)(ob + 4 * i);
      float4 wr = *(const float4*)(wrp + 4 * i);
      float4 wz = *(const float4*)(wzp + 4 * i);
      float4 wn = *(const float4*)(wnp + 4 * i);
      float4 ur = *(const float4*)(urp + 4 * i);
      float4 uz = *(const float4*)(uzp + 4 * i);
      float4 un = *(const float4*)(unp + 4 * i);
      ar += hv.x*wr.x + hv.y*wr.y + hv.z*wr.z + hv.w*wr.w;
      az += hv.x*wz.x + hv.y*wz.y + hv.z*wz.z + hv.w*wz.w;
      an += hv.x*wn.x + hv.y*wn.y + hv.z*wn.z + hv.w*wn.w;
      xr += ov.x*ur.x + ov.y*ur.y + ov.z*ur.z + ov.w*ur.w;
      xz += ov.x*uz.x + ov.y*uz.y + ov.z*uz.z + ov.w*uz.w;
      xn += ov.x*un.x + ov.y*un.y + ov.z*un.z + ov.w*un.w;
    }
  }
  ps[kq][0][rem] = ar; ps[kq][1][rem] = az; ps[kq][2][rem] = an;
  if (isB) { ps[kq][3][rem] = xr; ps[kq][4][rem] = xz; ps[kq][5][rem] = xn; }
  __syncthreads();

  if (lt < 128) {
    const int bb = lt >> 3;
    const int dg = dbase + (lt & 7);
    const float* bhh = isB ? bhh1 : bhh0;
    float ghr = ps[0][0][lt] + ps[1][0][lt] + ps[2][0][lt] + ps[3][0][lt] + bhh[dg];
    float ghz = ps[0][1][lt] + ps[1][1][lt] + ps[2][1][lt] + ps[3][1][lt] + bhh[512 + dg];
    float ghn = ps[0][2][lt] + ps[1][2][lt] + ps[2][2][lt] + ps[3][2][lt] + bhh[1024 + dg];
    float ixr, ixz, ixn;
    if (!isB) {
      const float* xrow = xg0 + (size_t)(bb * T_ + ts) * 1536;
      ixr = xrow[dg]; ixz = xrow[512 + dg]; ixn = xrow[1024 + dg];
    } else {
      ixr = ps[0][3][lt] + ps[1][3][lt] + ps[2][3][lt] + ps[3][3][lt] + bih1[dg];
      ixz = ps[0][4][lt] + ps[1][4][lt] + ps[2][4][lt] + ps[3][4][lt] + bih1[512 + dg];
      ixn = ps[0][5][lt] + ps[1][5][lt] + ps[2][5][lt] + ps[3][5][lt] + bih1[1024 + dg];
    }
    float rr = 1.f / (1.f + expf(-(ixr + ghr)));
    float zz = 1.f / (1.f + expf(-(ixz + ghz)));
    float nn = tanhf(ixn + rr * ghn);
    float hp = ts ? ybuf[(size_t)(bb * T_ + ts - 1) * 512 + dg] : h0g[bb * 512 + dg];
    float hnew = (1.f - zz) * nn + zz * hp;
    ybuf[(size_t)(bb * T_ + ts) * 512 + dg] = hnew;
    if (ts == T_ - 1) hn[(isB ? 8192 : 0) + bb * 512 + dg] = hnew;
  }
}

// ---------------- attention: one WG per (b,t) row ----------------
__global__ __launch_bounds__(256) void k_attn(const float* __restrict__ y,
    const float* __restrict__ enc, float* __restrict__ aout)
{
  __shared__ float orow[512];
  __shared__ float wbuf[256];
  __shared__ float red[8];
  const int row = blockIdx.x;        // b*T+t
  const int b = row >> 7;
  const int lt = threadIdx.x;
  orow[lt]       = y[(size_t)row*512 + lt];
  orow[lt + 256] = y[(size_t)row*512 + lt + 256];
  __syncthreads();
  const float* er = enc + (size_t)(b*S_ + lt) * 512;
  float acc = 0.f;
  for (int k = 0; k < 512; k += 4) {
    float4 e = *(const float4*)(er + k);
    acc += orow[k]*e.x + orow[k+1]*e.y + orow[k+2]*e.z + orow[k+3]*e.w;
  }
  float m = acc;
#pragma unroll
  for (int off = 32; off > 0; off >>= 1) m = fmaxf(m, __shfl_down(m, off));
  if ((lt & 63) == 0) red[lt >> 6] = m;
  __syncthreads();
  float mx = fmaxf(fmaxf(red[0], red[1]), fmaxf(red[2], red[3]));
  float e = expf(acc - mx);
  wbuf[lt] = e;
  float s = e;
#pragma unroll
  for (int off = 32; off > 0; off >>= 1) s += __shfl_down(s, off);
  if ((lt & 63) == 0) red[4 + (lt >> 6)] = s;
  __syncthreads();
  const float inv = 1.f / (red[4] + red[5] + red[6] + red[7]);
  const int kk = lt * 2;
  float c0 = 0.f, c1 = 0.f;
  for (int s2 = 0; s2 < S_; ++s2) {
    float ws = wbuf[s2];
    float2 ev = *(const float2*)(enc + (size_t)(b*S_ + s2)*512 + kk);
    c0 += ws * ev.x; c1 += ws * ev.y;
  }
  aout[(size_t)row*512 + kk]     = orow[kk]     + c0 * inv;
  aout[(size_t)row*512 + kk + 1] = orow[kk + 1] + c1 * inv;
}

// ---------------- bf16 MFMA NT GEMM + bias for logits ----------------
// C[2048][32000] = A[2048][512] * B[32000][512]^T + bias, f32 in (cast to bf16
// on the fly during LDS staging), f32 out. 128x128 tile, 4 waves, 16x16x32 MFMA.
__device__ inline unsigned short f2bf(float f) {
  union { float f; unsigned u; } v; v.f = f;
  unsigned r = v.u + 0x7FFF + ((v.u >> 16) & 1);
  return (unsigned short)(r >> 16);
}

__global__ __launch_bounds__(256) void k_gemm_bf16(const float* __restrict__ A,
    const float* __restrict__ Bm, const float* __restrict__ bias,
    float* __restrict__ C)
{
  __shared__ unsigned short As[128 * 40];   // row stride 40 elems (80B) - bank-safe
  __shared__ unsigned short Bs[128 * 40];
  const int tid = threadIdx.x;
  const int nbase = blockIdx.x * 128;
  const int mbase = blockIdx.y * 128;
  const int wv = tid >> 6;
  const int l  = tid & 63;
  const int wr = wv >> 1, wc = wv & 1;
  const int r = l & 15, q = l >> 4;

  float4v acc[4][4];
#pragma unroll
  for (int mi = 0; mi < 4; ++mi)
#pragma unroll
    for (int ni = 0; ni < 4; ++ni)
      acc[mi][ni] = (float4v){0.f, 0.f, 0.f, 0.f};

  for (int k0 = 0; k0 < 512; k0 += 32) {
    __syncthreads();
#pragma unroll
    for (int h = 0; h < 2; ++h) {
      const int c = tid + h * 256;          // chunk 0..511
      const int row = c >> 2, cb = c & 3;   // 8 bf16 per chunk
      const float* Ag = A + (size_t)(mbase + row) * 512 + k0 + cb * 8;
      float4 f0 = *(const float4*)(Ag);
      float4 f1 = *(const float4*)(Ag + 4);
      union { short8v v; unsigned short u[8]; } pa;
      pa.u[0]=f2bf(f0.x); pa.u[1]=f2bf(f0.y); pa.u[2]=f2bf(f0.z); pa.u[3]=f2bf(f0.w);
      pa.u[4]=f2bf(f1.x); pa.u[5]=f2bf(f1.y); pa.u[6]=f2bf(f1.z); pa.u[7]=f2bf(f1.w);
      *(short8v*)&As[row * 40 + cb * 8] = pa.v;
      const float* Bg = Bm + (size_t)(nbase + row) * 512 + k0 + cb * 8;
      float4 g0 = *(const float4*)(Bg);
      float4 g1 = *(const float4*)(Bg + 4);
      union { short8v v; unsigned short u[8]; } pb;
      pb.u[0]=f2bf(g0.x); pb.u[1]=f2bf(g0.y); pb.u[2]=f2bf(g0.z); pb.u[3]=f2bf(g0.w);
      pb.u[4]=f2bf(g1.x); pb.u[5]=f2bf(g1.y); pb.u[6]=f2bf(g1.z); pb.u[7]=f2bf(g1.w);
      *(short8v*)&Bs[row * 40 + cb * 8] = pb.v;
    }
    __syncthreads();

    short8v af[4], bf[4];
#pragma unroll
    for (int mi = 0; mi < 4; ++mi)
      af[mi] = *(short8v*)&As[(wr * 64 + mi * 16 + r) * 40 + q * 8];
#pragma unroll
    for (int ni = 0; ni < 4; ++ni)
      bf[ni] = *(short8v*)&Bs[(wc * 64 + ni * 16 + r) * 40 + q * 8];
#pragma unroll
    for (int mi = 0; mi < 4; ++mi)
#pragma unroll
      for (int ni = 0; ni < 4; ++ni)
        acc[mi][ni] = __builtin_amdgcn_mfma_f32_16x16x32_bf16(af[mi], bf[ni], acc[mi][ni], 0, 0, 0);
  }

  const int mg = mbase + wr * 64;
  const int ng = nbase + wc * 64;
#pragma unroll
  for (int ni = 0; ni < 4; ++ni) {
    const int col = ng + ni * 16 + r;
    const float bj = bias[col];
#pragma unroll
    for (int mi = 0; mi < 4; ++mi) {
      const int rowb = mg + mi * 16 + q * 4;
      float4v v = acc[mi][ni];
      C[(size_t)(rowb + 0) * V_ + col] = v[0] + bj;
      C[(size_t)(rowb + 1) * V_ + col] = v[1] + bj;
      C[(size_t)(rowb + 2) * V_ + col] = v[2] + bj;
      C[(size_t)(rowb + 3) * V_ + col] = v[3] + bj;
    }
  }
}

extern "C" void kernel_launch(void* const* d_in, const int* in_sizes, int n_in,
                              void* d_out, int out_size, void* d_ws, size_t ws_size,
                              hipStream_t stream)
{
  const int*   tgt    = (const int*)  d_in[0];
  const float* hidden = (const float*)d_in[1];
  const float* enc    = (const float*)d_in[2];
  const float* embed  = (const float*)d_in[3];
  const float* W_ih0  = (const float*)d_in[4];
  const float* W_hh0  = (const float*)d_in[5];
  const float* b_ih0  = (const float*)d_in[6];
  const float* b_hh0  = (const float*)d_in[7];
  const float* W_ih1  = (const float*)d_in[8];
  const float* W_hh1  = (const float*)d_in[9];
  const float* b_ih1  = (const float*)d_in[10];
  const float* b_hh1  = (const float*)d_in[11];
  const float* W_out  = (const float*)d_in[12];
  const float* b_out  = (const float*)d_in[13];
  float* out = (float*)d_out;

  float* ws   = (float*)d_ws;
  float* xbuf = ws;                          // 2048*512   (x, later attn_out)
  float* xg   = ws + 1048576;                // 2048*1536  (layer-0 input gates)
  float* out0 = xg + 3145728;                // 2048*512
  float* y1   = out0 + 1048576;              // 2048*512

  const size_t logitsN = (size_t)(B_*T_) * V_;   // 65,536,000
  float* hn = out + logitsN;
  float* cn = hn + 16384;

  hipMemsetAsync(cn, 0, (size_t)16384 * sizeof(float), stream);   // cn = zeros

  k_gather<<<dim3(B_*T_), dim3(128), 0, stream>>>(tgt, embed, xbuf);
  k_gemm_nt_bias<<<dim3(1536/64, (B_*T_)/64), dim3(256), 0, stream>>>(xbuf, W_ih0, b_ih0, xg, 1536);
  for (int t = 0; t <= T_; ++t)
    k_step<<<dim3(128), dim3(512), 0, stream>>>(xg, W_hh0, b_hh0, W_ih1, b_ih1,
                                                W_hh1, b_hh1, hidden, out0, y1, hn, t);
  k_attn<<<dim3(B_*T_), dim3(256), 0, stream>>>(y1, enc, xbuf);
  k_gemm_bf16<<<dim3(V_/128, (B_*T_)/128), dim3(256), 0, stream>>>(xbuf, W_out, b_out, out);
}

// Round 5
// 3619.907 us; speedup vs baseline: 1.6027x; 1.1434x over previous
//
#include <hip/hip_runtime.h>
#include <hip/hip_bf16.h>
#include <math.h>

#define B_ 16
#define T_ 128
#define S_ 256
#define H_ 512
#define M_ 512
#define V_ 32000
#define SENT 0x7FC0DEADu

typedef __attribute__((ext_vector_type(8))) short short8v;
typedef __attribute__((ext_vector_type(4))) float float4v;

// ---------------- embedding gather ----------------
__global__ __launch_bounds__(128) void k_gather(const int* __restrict__ tgt,
    const float* __restrict__ embed, float* __restrict__ x)
{
  const int row = blockIdx.x;          // b*T+t
  const int v = tgt[row];
  const float4* src = (const float4*)(embed + (size_t)v * H_);
  float4* dst = (float4*)(x + (size_t)row * H_);
  dst[threadIdx.x] = src[threadIdx.x];
}

// ---------------- sentinel fill ----------------
__global__ __launch_bounds__(512) void k_fill(unsigned int* __restrict__ p, int n)
{
  const int i = blockIdx.x * 512 + threadIdx.x;
  if (i < n) p[i] = SENT;
}

// ---------------- f32 NT GEMM + bias (xg0 only) ----------------
__global__ __launch_bounds__(256) void k_gemm_nt_bias(const float* __restrict__ A,
    const float* __restrict__ Bm, const float* __restrict__ bias,
    float* __restrict__ C, int N)
{
  __shared__ float As[64][33];
  __shared__ float Bs[64][33];
  const int tid = threadIdx.x;
  const int tm = tid >> 4, tn = tid & 15;
  const float* Ab = A  + (size_t)blockIdx.y * 64 * 512;
  const float* Bb = Bm + (size_t)blockIdx.x * 64 * 512;
  float acc00=0.f,acc01=0.f,acc02=0.f,acc03=0.f;
  float acc10=0.f,acc11=0.f,acc12=0.f,acc13=0.f;
  float acc20=0.f,acc21=0.f,acc22=0.f,acc23=0.f;
  float acc30=0.f,acc31=0.f,acc32=0.f,acc33=0.f;
  for (int k0 = 0; k0 < 512; k0 += 32) {
#pragma unroll
    for (int i = 0; i < 8; ++i) {
      int v = tid + i * 256;
      int row = v >> 5, col = v & 31;
      As[row][col] = Ab[(size_t)row * 512 + k0 + col];
      Bs[row][col] = Bb[(size_t)row * 512 + k0 + col];
    }
    __syncthreads();
#pragma unroll
    for (int kk = 0; kk < 32; ++kk) {
      float a0 = As[tm*4+0][kk], a1 = As[tm*4+1][kk];
      float a2 = As[tm*4+2][kk], a3 = As[tm*4+3][kk];
      float b0 = Bs[tn*4+0][kk], b1 = Bs[tn*4+1][kk];
      float b2 = Bs[tn*4+2][kk], b3 = Bs[tn*4+3][kk];
      acc00 += a0*b0; acc01 += a0*b1; acc02 += a0*b2; acc03 += a0*b3;
      acc10 += a1*b0; acc11 += a1*b1; acc12 += a1*b2; acc13 += a1*b3;
      acc20 += a2*b0; acc21 += a2*b1; acc22 += a2*b2; acc23 += a2*b3;
      acc30 += a3*b0; acc31 += a3*b1; acc32 += a3*b2; acc33 += a3*b3;
    }
    __syncthreads();
  }
  const int mbase = blockIdx.y*64 + tm*4;
  const int nbase = blockIdx.x*64 + tn*4;
  float bj0 = bias[nbase+0], bj1 = bias[nbase+1], bj2 = bias[nbase+2], bj3 = bias[nbase+3];
  float* Cr0 = C + (size_t)(mbase+0)*N + nbase;
  float* Cr1 = C + (size_t)(mbase+1)*N + nbase;
  float* Cr2 = C + (size_t)(mbase+2)*N + nbase;
  float* Cr3 = C + (size_t)(mbase+3)*N + nbase;
  Cr0[0]=acc00+bj0; Cr0[1]=acc01+bj1; Cr0[2]=acc02+bj2; Cr0[3]=acc03+bj3;
  Cr1[0]=acc10+bj0; Cr1[1]=acc11+bj1; Cr1[2]=acc12+bj2; Cr1[3]=acc13+bj3;
  Cr2[0]=acc20+bj0; Cr2[1]=acc21+bj1; Cr2[2]=acc22+bj2; Cr2[3]=acc23+bj3;
  Cr3[0]=acc30+bj0; Cr3[1]=acc31+bj1; Cr3[2]=acc32+bj2; Cr3[3]=acc33+bj3;
}

// ---------------- fused 2-layer GRU, sentinel data-flow pipeline ----------------
// 128 WGs x 512 threads, persistent. WGs [0,64): layer 0; [64,128): layer 1.
// No flags, no fences: producers store h via relaxed agent atomics (write-through);
// consumers poll the data itself (sentinel 0x7FC0DEAD marks not-yet-written).
__global__ __launch_bounds__(512) void k_gru2(
    const float* __restrict__ xg0,
    const float* __restrict__ Whh0, const float* __restrict__ bhh0,
    const float* __restrict__ Wih1, const float* __restrict__ bih1,
    const float* __restrict__ Whh1, const float* __restrict__ bhh1,
    const float* __restrict__ hidden,
    float* __restrict__ out0, float* __restrict__ y1, float* __restrict__ hn)
{
  __shared__ float Wl[24][516];       // this WG's 24 W_hh rows (3 gates x 8 dims)
  __shared__ float hx[2][16 * 516];   // [0]: h_prev staged; [1]: out0[t] staged (layer 1)
  __shared__ float ps[4][6][128];     // matvec partials [k-quarter][gate][b*8+dl]
  const int bid = blockIdx.x;
  const bool isB = bid >= 64;
  const int wg = bid & 63;
  const int dbase = wg * 8;
  const int lt = threadIdx.x;
  const float* Whh = isB ? Whh1 : Whh0;
  for (int r = 0; r < 24; ++r)
    Wl[r][lt] = Whh[(size_t)((r >> 3) * 512 + dbase + (r & 7)) * 512 + lt];

  const int kq  = lt >> 7;            // k-quarter 0..3
  const int rem = lt & 127;
  const int b   = rem >> 3;           // batch
  const int dl  = rem & 7;            // local dim
  const int k0  = kq << 7;
  const int sb  = lt >> 5;            // staging batch 0..15
  const int sc  = lt & 31;            // staging lane 0..31
  float* ybuf = isB ? y1 : out0;
  const float* h0g = hidden + (isB ? 8192 : 0);
  const float* wrp = &Wl[dl][k0];
  const float* wzp = &Wl[8 + dl][k0];
  const float* wnp = &Wl[16 + dl][k0];
  const float* urp = Wih1 + (size_t)(       dbase + dl) * 512 + k0;
  const float* uzp = Wih1 + (size_t)( 512 + dbase + dl) * 512 + k0;
  const float* unp = Wih1 + (size_t)(1024 + dbase + dl) * 512 + k0;
  // final-phase per-thread constants (threads lt<128)
  const int bb = lt >> 3;
  const int dg = dbase + (lt & 7);
  float bhr = 0.f, bhz = 0.f, bhn = 0.f, bir = 0.f, biz = 0.f, bin_ = 0.f;
  if (lt < 128) {
    const float* bhh = isB ? bhh1 : bhh0;
    bhr = bhh[dg]; bhz = bhh[512 + dg]; bhn = bhh[1024 + dg];
    if (isB) { bir = bih1[dg]; biz = bih1[512 + dg]; bin_ = bih1[1024 + dg]; }
  }

  // poll 16 elements (this thread's slice) until none is sentinel, then -> LDS
  auto poll16 = [&](const float* src, float* dst) {
    float v[16];
#pragma unroll
    for (int j = 0; j < 16; ++j)
      v[j] = __hip_atomic_load(src + sc + j * 32, __ATOMIC_RELAXED, __HIP_MEMORY_SCOPE_AGENT);
    for (;;) {
      bool any = false;
#pragma unroll
      for (int j = 0; j < 16; ++j) any |= (__float_as_uint(v[j]) == SENT);
      if (!any) break;
      __builtin_amdgcn_s_sleep(1);
#pragma unroll
      for (int j = 0; j < 16; ++j)
        if (__float_as_uint(v[j]) == SENT)
          v[j] = __hip_atomic_load(src + sc + j * 32, __ATOMIC_RELAXED, __HIP_MEMORY_SCOPE_AGENT);
    }
#pragma unroll
    for (int j = 0; j < 16; ++j) dst[sc + j * 32] = v[j];
  };

  for (int t = 0; t < T_; ++t) {
    // ---- stage h_prev (and out0[t] for layer 1) ----
    if (t == 0) {
#pragma unroll
      for (int j = 0; j < 16; ++j)
        hx[0][sb * 516 + sc + j * 32] = h0g[sb * 512 + sc + j * 32];
    } else {
      poll16(ybuf + (size_t)(sb * T_ + t - 1) * 512, &hx[0][sb * 516]);
    }
    if (isB)
      poll16(out0 + (size_t)(sb * T_ + t) * 512, &hx[1][sb * 516]);
    __syncthreads();

    // ---- matvec from LDS ----
    float ar = 0.f, az = 0.f, an = 0.f, xr = 0.f, xz = 0.f, xn = 0.f;
    const float* hb = &hx[0][b * 516 + k0];
    if (!isB) {
#pragma unroll
      for (int i = 0; i < 32; ++i) {
        float4 hv = *(const float4*)(hb + 4 * i);
        float4 wr = *(const float4*)(wrp + 4 * i);
        float4 wz = *(const float4*)(wzp + 4 * i);
        float4 wn = *(const float4*)(wnp + 4 * i);
        ar += hv.x*wr.x + hv.y*wr.y + hv.z*wr.z + hv.w*wr.w;
        az += hv.x*wz.x + hv.y*wz.y + hv.z*wz.z + hv.w*wz.w;
        an += hv.x*wn.x + hv.y*wn.y + hv.z*wn.z + hv.w*wn.w;
      }
    } else {
      const float* ob = &hx[1][b * 516 + k0];
#pragma unroll
      for (int i = 0; i < 32; ++i) {
        float4 hv = *(const float4*)(hb + 4 * i);
        float4 ov = *(const float4*)(ob + 4 * i);
        float4 wr = *(const float4*)(wrp + 4 * i);
        float4 wz = *(const float4*)(wzp + 4 * i);
        float4 wn = *(const float4*)(wnp + 4 * i);
        float4 ur = *(const float4*)(urp + 4 * i);
        float4 uz = *(const float4*)(uzp + 4 * i);
        float4 un = *(const float4*)(unp + 4 * i);
        ar += hv.x*wr.x + hv.y*wr.y + hv.z*wr.z + hv.w*wr.w;
        az += hv.x*wz.x + hv.y*wz.y + hv.z*wz.z + hv.w*wz.w;
        an += hv.x*wn.x + hv.y*wn.y + hv.z*wn.z + hv.w*wn.w;
        xr += ov.x*ur.x + ov.y*ur.y + ov.z*ur.z + ov.w*ur.w;
        xz += ov.x*uz.x + ov.y*uz.y + ov.z*uz.z + ov.w*uz.w;
        xn += ov.x*un.x + ov.y*un.y + ov.z*un.z + ov.w*un.w;
      }
    }
    ps[kq][0][rem] = ar; ps[kq][1][rem] = az; ps[kq][2][rem] = an;
    if (isB) { ps[kq][3][rem] = xr; ps[kq][4][rem] = xz; ps[kq][5][rem] = xn; }
    __syncthreads();

    // ---- reduce + activations + state update (threads 0..127) ----
    if (lt < 128) {
      float ghr = ps[0][0][lt] + ps[1][0][lt] + ps[2][0][lt] + ps[3][0][lt] + bhr;
      float ghz = ps[0][1][lt] + ps[1][1][lt] + ps[2][1][lt] + ps[3][1][lt] + bhz;
      float ghn = ps[0][2][lt] + ps[1][2][lt] + ps[2][2][lt] + ps[3][2][lt] + bhn;
      float ixr, ixz, ixn;
      if (!isB) {
        const float* xrow = xg0 + (size_t)(bb * T_ + t) * 1536;
        ixr = xrow[dg]; ixz = xrow[512 + dg]; ixn = xrow[1024 + dg];
      } else {
        ixr = ps[0][3][lt] + ps[1][3][lt] + ps[2][3][lt] + ps[3][3][lt] + bir;
        ixz = ps[0][4][lt] + ps[1][4][lt] + ps[2][4][lt] + ps[3][4][lt] + biz;
        ixn = ps[0][5][lt] + ps[1][5][lt] + ps[2][5][lt] + ps[3][5][lt] + bin_;
      }
      float rr = 1.f / (1.f + expf(-(ixr + ghr)));
      float zz = 1.f / (1.f + expf(-(ixz + ghz)));
      float nn = tanhf(ixn + rr * ghn);
      float hp = hx[0][bb * 516 + dg];
      float hnew = (1.f - zz) * nn + zz * hp;
      __hip_atomic_store(&ybuf[(size_t)(bb * T_ + t) * 512 + dg], hnew,
                         __ATOMIC_RELAXED, __HIP_MEMORY_SCOPE_AGENT);
      if (t == T_ - 1) hn[(isB ? 8192 : 0) + bb * 512 + dg] = hnew;
    }
    // no trailing barrier: next iteration's staging only overwrites hx after
    // poll success, and ps readers passed the barrier above
  }
}

// ---------------- attention: one WG per (b,t) row ----------------
__global__ __launch_bounds__(256) void k_attn(const float* __restrict__ y,
    const float* __restrict__ enc, float* __restrict__ aout)
{
  __shared__ float orow[512];
  __shared__ float wbuf[256];
  __shared__ float red[8];
  const int row = blockIdx.x;        // b*T+t
  const int b = row >> 7;
  const int lt = threadIdx.x;
  orow[lt]       = y[(size_t)row*512 + lt];
  orow[lt + 256] = y[(size_t)row*512 + lt + 256];
  __syncthreads();
  const float* er = enc + (size_t)(b*S_ + lt) * 512;
  float acc = 0.f;
  for (int k = 0; k < 512; k += 4) {
    float4 e = *(const float4*)(er + k);
    acc += orow[k]*e.x + orow[k+1]*e.y + orow[k+2]*e.z + orow[k+3]*e.w;
  }
  float m = acc;
#pragma unroll
  for (int off = 32; off > 0; off >>= 1) m = fmaxf(m, __shfl_down(m, off));
  if ((lt & 63) == 0) red[lt >> 6] = m;
  __syncthreads();
  float mx = fmaxf(fmaxf(red[0], red[1]), fmaxf(red[2], red[3]));
  float e = expf(acc - mx);
  wbuf[lt] = e;
  float s = e;
#pragma unroll
  for (int off = 32; off > 0; off >>= 1) s += __shfl_down(s, off);
  if ((lt & 63) == 0) red[4 + (lt >> 6)] = s;
  __syncthreads();
  const float inv = 1.f / (red[4] + red[5] + red[6] + red[7]);
  const int kk = lt * 2;
  float c0 = 0.f, c1 = 0.f;
  for (int s2 = 0; s2 < S_; ++s2) {
    float ws = wbuf[s2];
    float2 ev = *(const float2*)(enc + (size_t)(b*S_ + s2)*512 + kk);
    c0 += ws * ev.x; c1 += ws * ev.y;
  }
  aout[(size_t)row*512 + kk]     = orow[kk]     + c0 * inv;
  aout[(size_t)row*512 + kk + 1] = orow[kk + 1] + c1 * inv;
}

// ---------------- bf16 MFMA NT GEMM + bias for logits ----------------
__global__ __launch_bounds__(256) void k_gemm_bf16(const float* __restrict__ A,
    const float* __restrict__ Bm, const float* __restrict__ bias,
    float* __restrict__ C)
{
  __shared__ unsigned short As[128 * 40];
  __shared__ unsigned short Bs[128 * 40];
  const int tid = threadIdx.x;
  const int nbase = blockIdx.x * 128;
  const int mbase = blockIdx.y * 128;
  const int wv = tid >> 6;
  const int l  = tid & 63;
  const int wr = wv >> 1, wc = wv & 1;
  const int r = l & 15, q = l >> 4;

  float4v acc[4][4];
#pragma unroll
  for (int mi = 0; mi < 4; ++mi)
#pragma unroll
    for (int ni = 0; ni < 4; ++ni)
      acc[mi][ni] = (float4v){0.f, 0.f, 0.f, 0.f};

  for (int k0 = 0; k0 < 512; k0 += 32) {
    __syncthreads();
#pragma unroll
    for (int h = 0; h < 2; ++h) {
      const int c = tid + h * 256;
      const int row = c >> 2, cb = c & 3;
      const float* Ag = A + (size_t)(mbase + row) * 512 + k0 + cb * 8;
      float4 f0 = *(const float4*)(Ag);
      float4 f1 = *(const float4*)(Ag + 4);
      union { short8v v; __hip_bfloat162 h2[4]; } pa;
      pa.h2[0] = __float22bfloat162_rn({f0.x, f0.y});
      pa.h2[1] = __float22bfloat162_rn({f0.z, f0.w});
      pa.h2[2] = __float22bfloat162_rn({f1.x, f1.y});
      pa.h2[3] = __float22bfloat162_rn({f1.z, f1.w});
      *(short8v*)&As[row * 40 + cb * 8] = pa.v;
      const float* Bg = Bm + (size_t)(nbase + row) * 512 + k0 + cb * 8;
      float4 g0 = *(const float4*)(Bg);
      float4 g1 = *(const float4*)(Bg + 4);
      union { short8v v; __hip_bfloat162 h2[4]; } pb;
      pb.h2[0] = __float22bfloat162_rn({g0.x, g0.y});
      pb.h2[1] = __float22bfloat162_rn({g0.z, g0.w});
      pb.h2[2] = __float22bfloat162_rn({g1.x, g1.y});
      pb.h2[3] = __float22bfloat162_rn({g1.z, g1.w});
      *(short8v*)&Bs[row * 40 + cb * 8] = pb.v;
    }
    __syncthreads();

    short8v af[4], bf[4];
#pragma unroll
    for (int mi = 0; mi < 4; ++mi)
      af[mi] = *(short8v*)&As[(wr * 64 + mi * 16 + r) * 40 + q * 8];
#pragma unroll
    for (int ni = 0; ni < 4; ++ni)
      bf[ni] = *(short8v*)&Bs[(wc * 64 + ni * 16 + r) * 40 + q * 8];
#pragma unroll
    for (int mi = 0; mi < 4; ++mi)
#pragma unroll
      for (int ni = 0; ni < 4; ++ni)
        acc[mi][ni] = __builtin_amdgcn_mfma_f32_16x16x32_bf16(af[mi], bf[ni], acc[mi][ni], 0, 0, 0);
  }

  const int mg = mbase + wr * 64;
  const int ng = nbase + wc * 64;
#pragma unroll
  for (int ni = 0; ni < 4; ++ni) {
    const int col = ng + ni * 16 + r;
    const float bj = bias[col];
#pragma unroll
    for (int mi = 0; mi < 4; ++mi) {
      const int rowb = mg + mi * 16 + q * 4;
      float4v v = acc[mi][ni];
      C[(size_t)(rowb + 0) * V_ + col] = v[0] + bj;
      C[(size_t)(rowb + 1) * V_ + col] = v[1] + bj;
      C[(size_t)(rowb + 2) * V_ + col] = v[2] + bj;
      C[(size_t)(rowb + 3) * V_ + col] = v[3] + bj;
    }
  }
}

extern "C" void kernel_launch(void* const* d_in, const int* in_sizes, int n_in,
                              void* d_out, int out_size, void* d_ws, size_t ws_size,
                              hipStream_t stream)
{
  const int*   tgt    = (const int*)  d_in[0];
  const float* hidden = (const float*)d_in[1];
  const float* enc    = (const float*)d_in[2];
  const float* embed  = (const float*)d_in[3];
  const float* W_ih0  = (const float*)d_in[4];
  const float* W_hh0  = (const float*)d_in[5];
  const float* b_ih0  = (const float*)d_in[6];
  const float* b_hh0  = (const float*)d_in[7];
  const float* W_ih1  = (const float*)d_in[8];
  const float* W_hh1  = (const float*)d_in[9];
  const float* b_ih1  = (const float*)d_in[10];
  const float* b_hh1  = (const float*)d_in[11];
  const float* W_out  = (const float*)d_in[12];
  const float* b_out  = (const float*)d_in[13];
  float* out = (float*)d_out;

  float* ws   = (float*)d_ws;
  float* xbuf = ws;                          // 2048*512   (x, later attn_out)
  float* xg   = ws + 1048576;                // 2048*1536  (layer-0 input gates)
  float* out0 = xg + 3145728;                // 2048*512
  float* y1   = out0 + 1048576;              // 2048*512  (contiguous after out0)

  const size_t logitsN = (size_t)(B_*T_) * V_;   // 65,536,000
  float* hn = out + logitsN;
  float* cn = hn + 16384;

  hipMemsetAsync(cn, 0, (size_t)16384 * sizeof(float), stream);   // cn = zeros

  k_gather<<<dim3(B_*T_), dim3(128), 0, stream>>>(tgt, embed, xbuf);
  k_fill<<<dim3(4096), dim3(512), 0, stream>>>((unsigned int*)out0, 2097152);  // out0+y1 -> sentinel
  k_gemm_nt_bias<<<dim3(1536/64, (B_*T_)/64), dim3(256), 0, stream>>>(xbuf, W_ih0, b_ih0, xg, 1536);
  k_gru2<<<dim3(128), dim3(512), 0, stream>>>(xg, W_hh0, b_hh0, W_ih1, b_ih1,
                                              W_hh1, b_hh1, hidden, out0, y1, hn);
  k_attn<<<dim3(B_*T_), dim3(256), 0, stream>>>(y1, enc, xbuf);
  k_gemm_bf16<<<dim3(V_/128, (B_*T_)/128), dim3(256), 0, stream>>>(xbuf, W_out, b_out, out);
}

// Round 6
// 2579.843 us; speedup vs baseline: 2.2488x; 1.4032x over previous
//
#include <hip/hip_runtime.h>
#include <hip/hip_bf16.h>
#include <math.h>

#define B_ 16
#define T_ 128
#define S_ 256
#define H_ 512
#define M_ 512
#define V_ 32000
#define SENT 0x7FC0DEADu

typedef __attribute__((ext_vector_type(8))) short short8v;
typedef __attribute__((ext_vector_type(4))) float float4v;

// ---------------- embedding gather ----------------
__global__ __launch_bounds__(128) void k_gather(const int* __restrict__ tgt,
    const float* __restrict__ embed, float* __restrict__ x)
{
  const int row = blockIdx.x;          // b*T+t
  const int v = tgt[row];
  const float4* src = (const float4*)(embed + (size_t)v * H_);
  float4* dst = (float4*)(x + (size_t)row * H_);
  dst[threadIdx.x] = src[threadIdx.x];
}

// ---------------- sentinel fill ----------------
__global__ __launch_bounds__(512) void k_fill(unsigned int* __restrict__ p, int n)
{
  const int i = blockIdx.x * 512 + threadIdx.x;
  if (i < n) p[i] = SENT;
}

// ---------------- f32 NT GEMM + bias (xg0 only) ----------------
__global__ __launch_bounds__(256) void k_gemm_nt_bias(const float* __restrict__ A,
    const float* __restrict__ Bm, const float* __restrict__ bias,
    float* __restrict__ C, int N)
{
  __shared__ float As[64][33];
  __shared__ float Bs[64][33];
  const int tid = threadIdx.x;
  const int tm = tid >> 4, tn = tid & 15;
  const float* Ab = A  + (size_t)blockIdx.y * 64 * 512;
  const float* Bb = Bm + (size_t)blockIdx.x * 64 * 512;
  float acc00=0.f,acc01=0.f,acc02=0.f,acc03=0.f;
  float acc10=0.f,acc11=0.f,acc12=0.f,acc13=0.f;
  float acc20=0.f,acc21=0.f,acc22=0.f,acc23=0.f;
  float acc30=0.f,acc31=0.f,acc32=0.f,acc33=0.f;
  for (int k0 = 0; k0 < 512; k0 += 32) {
#pragma unroll
    for (int i = 0; i < 8; ++i) {
      int v = tid + i * 256;
      int row = v >> 5, col = v & 31;
      As[row][col] = Ab[(size_t)row * 512 + k0 + col];
      Bs[row][col] = Bb[(size_t)row * 512 + k0 + col];
    }
    __syncthreads();
#pragma unroll
    for (int kk = 0; kk < 32; ++kk) {
      float a0 = As[tm*4+0][kk], a1 = As[tm*4+1][kk];
      float a2 = As[tm*4+2][kk], a3 = As[tm*4+3][kk];
      float b0 = Bs[tn*4+0][kk], b1 = Bs[tn*4+1][kk];
      float b2 = Bs[tn*4+2][kk], b3 = Bs[tn*4+3][kk];
      acc00 += a0*b0; acc01 += a0*b1; acc02 += a0*b2; acc03 += a0*b3;
      acc10 += a1*b0; acc11 += a1*b1; acc12 += a1*b2; acc13 += a1*b3;
      acc20 += a2*b0; acc21 += a2*b1; acc22 += a2*b2; acc23 += a2*b3;
      acc30 += a3*b0; acc31 += a3*b1; acc32 += a3*b2; acc33 += a3*b3;
    }
    __syncthreads();
  }
  const int mbase = blockIdx.y*64 + tm*4;
  const int nbase = blockIdx.x*64 + tn*4;
  float bj0 = bias[nbase+0], bj1 = bias[nbase+1], bj2 = bias[nbase+2], bj3 = bias[nbase+3];
  float* Cr0 = C + (size_t)(mbase+0)*N + nbase;
  float* Cr1 = C + (size_t)(mbase+1)*N + nbase;
  float* Cr2 = C + (size_t)(mbase+2)*N + nbase;
  float* Cr3 = C + (size_t)(mbase+3)*N + nbase;
  Cr0[0]=acc00+bj0; Cr0[1]=acc01+bj1; Cr0[2]=acc02+bj2; Cr0[3]=acc03+bj3;
  Cr1[0]=acc10+bj0; Cr1[1]=acc11+bj1; Cr1[2]=acc12+bj2; Cr1[3]=acc13+bj3;
  Cr2[0]=acc20+bj0; Cr2[1]=acc21+bj1; Cr2[2]=acc22+bj2; Cr2[3]=acc23+bj3;
  Cr3[0]=acc30+bj0; Cr3[1]=acc31+bj1; Cr3[2]=acc32+bj2; Cr3[3]=acc33+bj3;
}

// ---------------- fused 2-layer GRU, register-tiled + heaters ----------------
// Grid 256 x 256 thr. WGs [0,64): layer 0, 8 dims each. WGs [64,192): layer 1,
// 4 dims each (W_ih1 slice also in LDS). WGs [192,256): FMA heaters (hold SCLK
// up; exit when y1's last element is produced). Sync = round-5 sentinel flow.
__global__ __launch_bounds__(256) void k_gru2(
    const float* __restrict__ xg0,
    const float* __restrict__ Whh0, const float* __restrict__ bhh0,
    const float* __restrict__ Wih1, const float* __restrict__ bih1,
    const float* __restrict__ Whh1, const float* __restrict__ bhh1,
    const float* __restrict__ hidden,
    float* __restrict__ out0, float* __restrict__ y1, float* __restrict__ hn)
{
  __shared__ float Wl[24][516];       // 24 weight rows (L0: Whh; L1: 12 Whh + 12 Wih)
  __shared__ float hx[2][16 * 516];   // [0]: h_prev; [1]: out0[t] (L1 only)
  __shared__ float ps[24][16][17];    // partials [row][batch][kq], padded
  const int bid = blockIdx.x;
  const int lt = threadIdx.x;

  // ---------------- heaters ----------------
  if (bid >= 192) {
    __shared__ int done;
    if (lt == 0) done = 0;
    __syncthreads();
    const float* flag = y1 + (size_t)(15 * T_ + 127) * 512 + 511;
    float a0 = 1.0f + lt, a1 = 2.0f + lt, a2 = 3.0f, a3 = 4.0f;
    const float mb = 1.0001f, cb = 0.9999f;
    for (;;) {
#pragma unroll 16
      for (int i = 0; i < 512; ++i) {
        a0 = __builtin_fmaf(a0, mb, cb); a1 = __builtin_fmaf(a1, mb, cb);
        a2 = __builtin_fmaf(a2, mb, cb); a3 = __builtin_fmaf(a3, mb, cb);
      }
      if (lt == 0 &&
          __float_as_uint(__hip_atomic_load(flag, __ATOMIC_RELAXED,
                                            __HIP_MEMORY_SCOPE_AGENT)) != SENT)
        done = 1;
      __syncthreads();
      if (done) break;
    }
    asm volatile("" :: "v"(a0), "v"(a1), "v"(a2), "v"(a3));
    return;
  }

  const bool isB = bid >= 64;
  const int wg = isB ? bid - 64 : bid;            // L0: 0..63, L1: 0..127
  const int dbase = isB ? wg * 4 : wg * 8;
  const int nd = isB ? 4 : 8;                      // dims this WG owns

  // ---- load weight rows into LDS ----
  // L0: row r (0..23) = Whh0 row ((r>>3)*512 + dbase + (r&7))
  // L1: rows 0..11 = Whh1 row ((r>>2)*512 + dbase + (r&3));
  //     rows 12..23 = Wih1 row (((r-12)>>2)*512 + dbase + ((r-12)&3))
  for (int r = 0; r < 24; ++r) {
    const float* src;
    if (!isB) src = Whh0 + (size_t)((r >> 3) * 512 + dbase + (r & 7)) * 512;
    else if (r < 12) src = Whh1 + (size_t)((r >> 2) * 512 + dbase + (r & 3)) * 512;
    else { int rr = r - 12; src = Wih1 + (size_t)((rr >> 2) * 512 + dbase + (rr & 3)) * 512; }
    Wl[r][lt] = src[lt];
    Wl[r][lt + 256] = src[lt + 256];
  }

  // thread decomposition: 256 = rgrp(4 waves) x bq(4) x kq(16)
  const int kq = lt & 15;
  const int bq = (lt >> 4) & 3;
  const int rgrp = lt >> 6;
  const int sb = lt >> 4;            // staging batch 0..15
  const int sc = lt & 15;            // staging lane 0..15 (32 elems each, stride 16)
  float* ybuf = isB ? y1 : out0;
  const float* h0g = hidden + (isB ? 8192 : 0);

  // reducer constants
  const int rb = isB ? (lt >> 2) : (lt >> 3);        // batch
  const int rdl = isB ? (lt & 3) : (lt & 7);         // local dim
  const int rdg = dbase + rdl;                       // global dim
  const int nred = isB ? 64 : 128;
  float bhr = 0.f, bhz = 0.f, bhn = 0.f, bir = 0.f, biz = 0.f, bin_ = 0.f;
  if (lt < nred) {
    const float* bhh = isB ? bhh1 : bhh0;
    bhr = bhh[rdg]; bhz = bhh[512 + rdg]; bhn = bhh[1024 + rdg];
    if (isB) { bir = bih1[rdg]; biz = bih1[512 + rdg]; bin_ = bih1[1024 + rdg]; }
  }

  // poll 32 elements (stride 16) until none is sentinel, then write to LDS
  auto stage_poll = [&](const float* src, float* dst) {
    float v[32];
    unsigned int miss = 0xFFFFFFFFu;
    for (;;) {
      unsigned int m = miss; miss = 0u;
#pragma unroll
      for (int j = 0; j < 32; ++j) {
        if (m & (1u << j)) {
          v[j] = __hip_atomic_load(src + sc + j * 16, __ATOMIC_RELAXED,
                                   __HIP_MEMORY_SCOPE_AGENT);
          if (__float_as_uint(v[j]) == SENT) miss |= 1u << j;
        }
      }
      if (!miss) break;
      __builtin_amdgcn_s_sleep(2);
    }
#pragma unroll
    for (int j = 0; j < 32; ++j) dst[sc + j * 16] = v[j];
  };

  for (int t = 0; t < T_; ++t) {
    // ---- stage inputs ----
    if (t == 0) {
#pragma unroll
      for (int j = 0; j < 32; ++j)
        hx[0][sb * 516 + sc + j * 16] = h0g[sb * 512 + sc + j * 16];
    } else {
      stage_poll(ybuf + (size_t)(sb * T_ + t - 1) * 512, &hx[0][sb * 516]);
    }
    if (isB)
      stage_poll(out0 + (size_t)(sb * T_ + t) * 512, &hx[1][sb * 516]);
    __syncthreads();                                    // B1

    // ---- register-tiled matvec: 4 batches x 6 rows per thread ----
    const float* inb = (isB && rgrp >= 2) ? &hx[1][0] : &hx[0][0];
    float acc[6][4];
#pragma unroll
    for (int jr = 0; jr < 6; ++jr)
#pragma unroll
      for (int jb = 0; jb < 4; ++jb) acc[jr][jb] = 0.f;
#pragma unroll
    for (int i = 0; i < 8; ++i) {
      const int kb = kq * 4 + i * 64;
      float4 hv0 = *(const float4*)(inb + (bq * 4 + 0) * 516 + kb);
      float4 hv1 = *(const float4*)(inb + (bq * 4 + 1) * 516 + kb);
      float4 hv2 = *(const float4*)(inb + (bq * 4 + 2) * 516 + kb);
      float4 hv3 = *(const float4*)(inb + (bq * 4 + 3) * 516 + kb);
#pragma unroll
      for (int jr = 0; jr < 6; ++jr) {
        float4 wv = *(const float4*)(&Wl[rgrp * 6 + jr][kb]);
        acc[jr][0] += wv.x*hv0.x + wv.y*hv0.y + wv.z*hv0.z + wv.w*hv0.w;
        acc[jr][1] += wv.x*hv1.x + wv.y*hv1.y + wv.z*hv1.z + wv.w*hv1.w;
        acc[jr][2] += wv.x*hv2.x + wv.y*hv2.y + wv.z*hv2.z + wv.w*hv2.w;
        acc[jr][3] += wv.x*hv3.x + wv.y*hv3.y + wv.z*hv3.z + wv.w*hv3.w;
      }
    }
#pragma unroll
    for (int jr = 0; jr < 6; ++jr)
#pragma unroll
      for (int jb = 0; jb < 4; ++jb)
        ps[rgrp * 6 + jr][bq * 4 + jb][kq] = acc[jr][jb];
    __syncthreads();                                    // B2

    // ---- reduce + activations + state update ----
    if (lt < nred) {
      float ghr, ghz, ghn, ixr, ixz, ixn;
      if (!isB) {
        float s0 = 0.f, s1 = 0.f, s2 = 0.f;
#pragma unroll
        for (int q = 0; q < 16; ++q) {
          s0 += ps[rdl][rb][q];
          s1 += ps[8 + rdl][rb][q];
          s2 += ps[16 + rdl][rb][q];
        }
        ghr = s0 + bhr; ghz = s1 + bhz; ghn = s2 + bhn;
        const float* xrow = xg0 + (size_t)(rb * T_ + t) * 1536;
        ixr = xrow[rdg]; ixz = xrow[512 + rdg]; ixn = xrow[1024 + rdg];
      } else {
        float s0=0.f,s1=0.f,s2=0.f,s3=0.f,s4=0.f,s5=0.f;
#pragma unroll
        for (int q = 0; q < 16; ++q) {
          s0 += ps[rdl][rb][q];       s1 += ps[4 + rdl][rb][q];  s2 += ps[8 + rdl][rb][q];
          s3 += ps[12 + rdl][rb][q];  s4 += ps[16 + rdl][rb][q]; s5 += ps[20 + rdl][rb][q];
        }
        ghr = s0 + bhr; ghz = s1 + bhz; ghn = s2 + bhn;
        ixr = s3 + bir; ixz = s4 + biz; ixn = s5 + bin_;
      }
      float rr = 1.f / (1.f + expf(-(ixr + ghr)));
      float zz = 1.f / (1.f + expf(-(ixz + ghz)));
      float nn = tanhf(ixn + rr * ghn);
      float hp = hx[0][rb * 516 + rdg];
      float hnew = (1.f - zz) * nn + zz * hp;
      __hip_atomic_store(&ybuf[(size_t)(rb * T_ + t) * 512 + rdg], hnew,
                         __ATOMIC_RELAXED, __HIP_MEMORY_SCOPE_AGENT);
      if (t == T_ - 1) hn[(isB ? 8192 : 0) + rb * 512 + rdg] = hnew;
    }
    // no trailing barrier: next staging writes gated by poll success + B2
  }
}

// ---------------- attention: one WG per (b,t) row ----------------
__global__ __launch_bounds__(256) void k_attn(const float* __restrict__ y,
    const float* __restrict__ enc, float* __restrict__ aout)
{
  __shared__ float orow[512];
  __shared__ float wbuf[256];
  __shared__ float red[8];
  const int row = blockIdx.x;        // b*T+t
  const int b = row >> 7;
  const int lt = threadIdx.x;
  orow[lt]       = y[(size_t)row*512 + lt];
  orow[lt + 256] = y[(size_t)row*512 + lt + 256];
  __syncthreads();
  const float* er = enc + (size_t)(b*S_ + lt) * 512;
  float acc = 0.f;
  for (int k = 0; k < 512; k += 4) {
    float4 e = *(const float4*)(er + k);
    acc += orow[k]*e.x + orow[k+1]*e.y + orow[k+2]*e.z + orow[k+3]*e.w;
  }
  float m = acc;
#pragma unroll
  for (int off = 32; off > 0; off >>= 1) m = fmaxf(m, __shfl_down(m, off));
  if ((lt & 63) == 0) red[lt >> 6] = m;
  __syncthreads();
  float mx = fmaxf(fmaxf(red[0], red[1]), fmaxf(red[2], red[3]));
  float e = expf(acc - mx);
  wbuf[lt] = e;
  float s = e;
#pragma unroll
  for (int off = 32; off > 0; off >>= 1) s += __shfl_down(s, off);
  if ((lt & 63) == 0) red[4 + (lt >> 6)] = s;
  __syncthreads();
  const float inv = 1.f / (red[4] + red[5] + red[6] + red[7]);
  const int kk = lt * 2;
  float c0 = 0.f, c1 = 0.f;
  for (int s2 = 0; s2 < S_; ++s2) {
    float ws = wbuf[s2];
    float2 ev = *(const float2*)(enc + (size_t)(b*S_ + s2)*512 + kk);
    c0 += ws * ev.x; c1 += ws * ev.y;
  }
  aout[(size_t)row*512 + kk]     = orow[kk]     + c0 * inv;
  aout[(size_t)row*512 + kk + 1] = orow[kk + 1] + c1 * inv;
}

// ---------------- bf16 MFMA NT GEMM + bias for logits ----------------
__global__ __launch_bounds__(256) void k_gemm_bf16(const float* __restrict__ A,
    const float* __restrict__ Bm, const float* __restrict__ bias,
    float* __restrict__ C)
{
  __shared__ unsigned short As[128 * 40];
  __shared__ unsigned short Bs[128 * 40];
  const int tid = threadIdx.x;
  const int nbase = blockIdx.x * 128;
  const int mbase = blockIdx.y * 128;
  const int wv = tid >> 6;
  const int l  = tid & 63;
  const int wr = wv >> 1, wc = wv & 1;
  const int r = l & 15, q = l >> 4;

  float4v acc[4][4];
#pragma unroll
  for (int mi = 0; mi < 4; ++mi)
#pragma unroll
    for (int ni = 0; ni < 4; ++ni)
      acc[mi][ni] = (float4v){0.f, 0.f, 0.f, 0.f};

  for (int k0 = 0; k0 < 512; k0 += 32) {
    __syncthreads();
#pragma unroll
    for (int h = 0; h < 2; ++h) {
      const int c = tid + h * 256;
      const int row = c >> 2, cb = c & 3;
      const float* Ag = A + (size_t)(mbase + row) * 512 + k0 + cb * 8;
      float4 f0 = *(const float4*)(Ag);
      float4 f1 = *(const float4*)(Ag + 4);
      union { short8v v; __hip_bfloat162 h2[4]; } pa;
      pa.h2[0] = __float22bfloat162_rn({f0.x, f0.y});
      pa.h2[1] = __float22bfloat162_rn({f0.z, f0.w});
      pa.h2[2] = __float22bfloat162_rn({f1.x, f1.y});
      pa.h2[3] = __float22bfloat162_rn({f1.z, f1.w});
      *(short8v*)&As[row * 40 + cb * 8] = pa.v;
      const float* Bg = Bm + (size_t)(nbase + row) * 512 + k0 + cb * 8;
      float4 g0 = *(const float4*)(Bg);
      float4 g1 = *(const float4*)(Bg + 4);
      union { short8v v; __hip_bfloat162 h2[4]; } pb;
      pb.h2[0] = __float22bfloat162_rn({g0.x, g0.y});
      pb.h2[1] = __float22bfloat162_rn({g0.z, g0.w});
      pb.h2[2] = __float22bfloat162_rn({g1.x, g1.y});
      pb.h2[3] = __float22bfloat162_rn({g1.z, g1.w});
      *(short8v*)&Bs[row * 40 + cb * 8] = pb.v;
    }
    __syncthreads();

    short8v af[4], bf[4];
#pragma unroll
    for (int mi = 0; mi < 4; ++mi)
      af[mi] = *(short8v*)&As[(wr * 64 + mi * 16 + r) * 40 + q * 8];
#pragma unroll
    for (int ni = 0; ni < 4; ++ni)
      bf[ni] = *(short8v*)&Bs[(wc * 64 + ni * 16 + r) * 40 + q * 8];
#pragma unroll
    for (int mi = 0; mi < 4; ++mi)
#pragma unroll
      for (int ni = 0; ni < 4; ++ni)
        acc[mi][ni] = __builtin_amdgcn_mfma_f32_16x16x32_bf16(af[mi], bf[ni], acc[mi][ni], 0, 0, 0);
  }

  const int mg = mbase + wr * 64;
  const int ng = nbase + wc * 64;
#pragma unroll
  for (int ni = 0; ni < 4; ++ni) {
    const int col = ng + ni * 16 + r;
    const float bj = bias[col];
#pragma unroll
    for (int mi = 0; mi < 4; ++mi) {
      const int rowb = mg + mi * 16 + q * 4;
      float4v v = acc[mi][ni];
      C[(size_t)(rowb + 0) * V_ + col] = v[0] + bj;
      C[(size_t)(rowb + 1) * V_ + col] = v[1] + bj;
      C[(size_t)(rowb + 2) * V_ + col] = v[2] + bj;
      C[(size_t)(rowb + 3) * V_ + col] = v[3] + bj;
    }
  }
}

extern "C" void kernel_launch(void* const* d_in, const int* in_sizes, int n_in,
                              void* d_out, int out_size, void* d_ws, size_t ws_size,
                              hipStream_t stream)
{
  const int*   tgt    = (const int*)  d_in[0];
  const float* hidden = (const float*)d_in[1];
  const float* enc    = (const float*)d_in[2];
  const float* embed  = (const float*)d_in[3];
  const float* W_ih0  = (const float*)d_in[4];
  const float* W_hh0  = (const float*)d_in[5];
  const float* b_ih0  = (const float*)d_in[6];
  const float* b_hh0  = (const float*)d_in[7];
  const float* W_ih1  = (const float*)d_in[8];
  const float* W_hh1  = (const float*)d_in[9];
  const float* b_ih1  = (const float*)d_in[10];
  const float* b_hh1  = (const float*)d_in[11];
  const float* W_out  = (const float*)d_in[12];
  const float* b_out  = (const float*)d_in[13];
  float* out = (float*)d_out;

  float* ws   = (float*)d_ws;
  float* xbuf = ws;                          // 2048*512   (x, later attn_out)
  float* xg   = ws + 1048576;                // 2048*1536  (layer-0 input gates)
  float* out0 = xg + 3145728;                // 2048*512
  float* y1   = out0 + 1048576;              // 2048*512  (contiguous after out0)

  const size_t logitsN = (size_t)(B_*T_) * V_;   // 65,536,000
  float* hn = out + logitsN;
  float* cn = hn + 16384;

  hipMemsetAsync(cn, 0, (size_t)16384 * sizeof(float), stream);   // cn = zeros

  k_gather<<<dim3(B_*T_), dim3(128), 0, stream>>>(tgt, embed, xbuf);
  k_fill<<<dim3(4096), dim3(512), 0, stream>>>((unsigned int*)out0, 2097152);  // out0+y1 -> sentinel
  k_gemm_nt_bias<<<dim3(1536/64, (B_*T_)/64), dim3(256), 0, stream>>>(xbuf, W_ih0, b_ih0, xg, 1536);
  k_gru2<<<dim3(256), dim3(256), 0, stream>>>(xg, W_hh0, b_hh0, W_ih1, b_ih1,
                                              W_hh1, b_hh1, hidden, out0, y1, hn);
  k_attn<<<dim3(B_*T_), dim3(256), 0, stream>>>(y1, enc, xbuf);
  k_gemm_bf16<<<dim3(V_/128, (B_*T_)/128), dim3(256), 0, stream>>>(xbuf, W_out, b_out, out);
}

// Round 7
// 1401.585 us; speedup vs baseline: 4.1392x; 1.8407x over previous
//
#include <hip/hip_runtime.h>
#include <hip/hip_bf16.h>
#include <math.h>

#define B_ 16
#define T_ 128
#define S_ 256
#define H_ 512
#define M_ 512
#define V_ 32000

typedef __attribute__((ext_vector_type(8))) short short8v;
typedef __attribute__((ext_vector_type(4))) float float4v;

// ---------------- embedding gather ----------------
__global__ __launch_bounds__(128) void k_gather(const int* __restrict__ tgt,
    const float* __restrict__ embed, float* __restrict__ x)
{
  const int row = blockIdx.x;          // b*T+t
  const int v = tgt[row];
  const float4* src = (const float4*)(embed + (size_t)v * H_);
  float4* dst = (float4*)(x + (size_t)row * H_);
  dst[threadIdx.x] = src[threadIdx.x];
}

// ---------------- f32 NT GEMM + bias (xg0 only) ----------------
__global__ __launch_bounds__(256) void k_gemm_nt_bias(const float* __restrict__ A,
    const float* __restrict__ Bm, const float* __restrict__ bias,
    float* __restrict__ C, int N)
{
  __shared__ float As[64][33];
  __shared__ float Bs[64][33];
  const int tid = threadIdx.x;
  const int tm = tid >> 4, tn = tid & 15;
  const float* Ab = A  + (size_t)blockIdx.y * 64 * 512;
  const float* Bb = Bm + (size_t)blockIdx.x * 64 * 512;
  float acc00=0.f,acc01=0.f,acc02=0.f,acc03=0.f;
  float acc10=0.f,acc11=0.f,acc12=0.f,acc13=0.f;
  float acc20=0.f,acc21=0.f,acc22=0.f,acc23=0.f;
  float acc30=0.f,acc31=0.f,acc32=0.f,acc33=0.f;
  for (int k0 = 0; k0 < 512; k0 += 32) {
#pragma unroll
    for (int i = 0; i < 8; ++i) {
      int v = tid + i * 256;
      int row = v >> 5, col = v & 31;
      As[row][col] = Ab[(size_t)row * 512 + k0 + col];
      Bs[row][col] = Bb[(size_t)row * 512 + k0 + col];
    }
    __syncthreads();
#pragma unroll
    for (int kk = 0; kk < 32; ++kk) {
      float a0 = As[tm*4+0][kk], a1 = As[tm*4+1][kk];
      float a2 = As[tm*4+2][kk], a3 = As[tm*4+3][kk];
      float b0 = Bs[tn*4+0][kk], b1 = Bs[tn*4+1][kk];
      float b2 = Bs[tn*4+2][kk], b3 = Bs[tn*4+3][kk];
      acc00 += a0*b0; acc01 += a0*b1; acc02 += a0*b2; acc03 += a0*b3;
      acc10 += a1*b0; acc11 += a1*b1; acc12 += a1*b2; acc13 += a1*b3;
      acc20 += a2*b0; acc21 += a2*b1; acc22 += a2*b2; acc23 += a2*b3;
      acc30 += a3*b0; acc31 += a3*b1; acc32 += a3*b2; acc33 += a3*b3;
    }
    __syncthreads();
  }
  const int mbase = blockIdx.y*64 + tm*4;
  const int nbase = blockIdx.x*64 + tn*4;
  float bj0 = bias[nbase+0], bj1 = bias[nbase+1], bj2 = bias[nbase+2], bj3 = bias[nbase+3];
  float* Cr0 = C + (size_t)(mbase+0)*N + nbase;
  float* Cr1 = C + (size_t)(mbase+1)*N + nbase;
  float* Cr2 = C + (size_t)(mbase+2)*N + nbase;
  float* Cr3 = C + (size_t)(mbase+3)*N + nbase;
  Cr0[0]=acc00+bj0; Cr0[1]=acc01+bj1; Cr0[2]=acc02+bj2; Cr0[3]=acc03+bj3;
  Cr1[0]=acc10+bj0; Cr1[1]=acc11+bj1; Cr1[2]=acc12+bj2; Cr1[3]=acc13+bj3;
  Cr2[0]=acc20+bj0; Cr2[1]=acc21+bj1; Cr2[2]=acc22+bj2; Cr2[3]=acc23+bj3;
  Cr3[0]=acc30+bj0; Cr3[1]=acc31+bj1; Cr3[2]=acc32+bj2; Cr3[3]=acc33+bj3;
}

// bulk coherent load: 8x dwordx4 (one row of 128B-chunks), LLC-visible (sc0 sc1),
// single waitcnt INSIDE the asm block so outputs are genuinely ready at block end.
__device__ inline void bulk8_to_lds(const float* rowbase, int sc, float* dstrow)
{
  const float* p = rowbase + sc * 4;            // float4 index sc
  float4 a, b, c, d, e, f, g, h;
  asm volatile(
    "global_load_dwordx4 %0, %[p], off sc0 sc1\n\t"
    "global_load_dwordx4 %1, %[p], off offset:256 sc0 sc1\n\t"
    "global_load_dwordx4 %2, %[p], off offset:512 sc0 sc1\n\t"
    "global_load_dwordx4 %3, %[p], off offset:768 sc0 sc1\n\t"
    "global_load_dwordx4 %4, %[p], off offset:1024 sc0 sc1\n\t"
    "global_load_dwordx4 %5, %[p], off offset:1280 sc0 sc1\n\t"
    "global_load_dwordx4 %6, %[p], off offset:1536 sc0 sc1\n\t"
    "global_load_dwordx4 %7, %[p], off offset:1792 sc0 sc1\n\t"
    "s_waitcnt vmcnt(0)"
    : "=&v"(a), "=&v"(b), "=&v"(c), "=&v"(d),
      "=&v"(e), "=&v"(f), "=&v"(g), "=&v"(h)
    : [p]"v"(p)
    : "memory");
  *(float4*)&dstrow[(0*16 + sc) * 4] = a;
  *(float4*)&dstrow[(1*16 + sc) * 4] = b;
  *(float4*)&dstrow[(2*16 + sc) * 4] = c;
  *(float4*)&dstrow[(3*16 + sc) * 4] = d;
  *(float4*)&dstrow[(4*16 + sc) * 4] = e;
  *(float4*)&dstrow[(5*16 + sc) * 4] = f;
  *(float4*)&dstrow[(6*16 + sc) * 4] = g;
  *(float4*)&dstrow[(7*16 + sc) * 4] = h;
}

// ---------------- fused 2-layer GRU: flag sync + bulk 16B transport ----------------
// Grid 256 x 256 thr. WGs [0,64): layer 0 (8 dims). WGs [64,192): layer 1 (4 dims,
// Whh1+Wih1 slices in LDS). WGs [192,256): FMA heaters (exit on last L1 flag).
// Producer: data stores (relaxed agent) -> __syncthreads (vmcnt0 drain) -> 1 flag.
// Consumer: 1-flag-per-lane poll -> bulk sc0sc1 dwordx4 loads -> LDS -> matvec.
__global__ __launch_bounds__(256) void k_gru2(
    const float* __restrict__ xg0,
    const float* __restrict__ Whh0, const float* __restrict__ bhh0,
    const float* __restrict__ Wih1, const float* __restrict__ bih1,
    const float* __restrict__ Whh1, const float* __restrict__ bhh1,
    const float* __restrict__ hidden,
    float* __restrict__ out0, float* __restrict__ y1, float* __restrict__ hn,
    unsigned int* __restrict__ fA, unsigned int* __restrict__ fB)
{
  __shared__ float Wl[24][520];       // weight rows (L0: Whh0; L1: 12 Whh1 + 12 Wih1)
  __shared__ float hx[2][16 * 520];   // [0]: h_prev; [1]: out0[t] (L1 only)
  __shared__ float ps[24][16][17];    // matvec partials [row][batch][kq]
  const int bid = blockIdx.x;
  const int lt = threadIdx.x;

  // ---------------- heaters ----------------
  if (bid >= 192) {
    __shared__ int done;
    if (lt == 0) done = 0;
    __syncthreads();
    const unsigned int* flag = &fB[(T_ - 1) * 128 + (bid - 192)];
    float a0 = 1.0f + lt, a1 = 2.0f + lt, a2 = 3.0f, a3 = 4.0f;
    const float mb = 1.0001f, cb = 0.9999f;
    for (;;) {
#pragma unroll 16
      for (int i = 0; i < 512; ++i) {
        a0 = __builtin_fmaf(a0, mb, cb); a1 = __builtin_fmaf(a1, mb, cb);
        a2 = __builtin_fmaf(a2, mb, cb); a3 = __builtin_fmaf(a3, mb, cb);
      }
      if (lt == 0 &&
          __hip_atomic_load(flag, __ATOMIC_RELAXED, __HIP_MEMORY_SCOPE_AGENT) != 0u)
        done = 1;
      __syncthreads();
      if (done) break;
    }
    asm volatile("" :: "v"(a0), "v"(a1), "v"(a2), "v"(a3));
    return;
  }

  const bool isB = bid >= 64;
  const int wg = isB ? bid - 64 : bid;            // L0: 0..63, L1: 0..127
  const int dbase = isB ? wg * 4 : wg * 8;

  // ---- stage weight rows into LDS ----
  for (int r = 0; r < 24; ++r) {
    const float* src;
    if (!isB) src = Whh0 + (size_t)((r >> 3) * 512 + dbase + (r & 7)) * 512;
    else if (r < 12) src = Whh1 + (size_t)((r >> 2) * 512 + dbase + (r & 3)) * 512;
    else { int rr = r - 12; src = Wih1 + (size_t)((rr >> 2) * 512 + dbase + (rr & 3)) * 512; }
    Wl[r][lt] = src[lt];
    Wl[r][lt + 256] = src[lt + 256];
  }

  const int kq = lt & 15;            // k-quarter lane
  const int bq = (lt >> 4) & 3;      // batch quad
  const int rgrp = lt >> 6;          // row group (wave)
  const int sb = lt >> 4;            // staging batch 0..15
  const int sc = lt & 15;            // staging float4-lane 0..15
  float* ybuf = isB ? y1 : out0;
  const float* h0g = hidden + (isB ? 8192 : 0);

  // reducer constants
  const int rb = isB ? (lt >> 2) : (lt >> 3);
  const int rdl = isB ? (lt & 3) : (lt & 7);
  const int rdg = dbase + rdl;
  const int nred = isB ? 64 : 128;
  float bhr = 0.f, bhz = 0.f, bhn = 0.f, bir = 0.f, biz = 0.f, bin_ = 0.f;
  if (lt < nred) {
    const float* bhh = isB ? bhh1 : bhh0;
    bhr = bhh[rdg]; bhz = bhh[512 + rdg]; bhn = bhh[1024 + rdg];
    if (isB) { bir = bih1[rdg]; biz = bih1[512 + rdg]; bin_ = bih1[1024 + rdg]; }
  }

  for (int t = 0; t < T_; ++t) {
    // ---- P: poll flags (one flag per lane, 1 transaction per retry) ----
    if (!isB) {
      if (t > 0 && lt < 64) {
        unsigned v;
        do {
          v = __hip_atomic_load(&fA[(t - 1) * 64 + lt], __ATOMIC_RELAXED, __HIP_MEMORY_SCOPE_AGENT);
          if (__all(v != 0u)) break;
          __builtin_amdgcn_s_sleep(1);
        } while (true);
      }
    } else {
      if (lt < 64) {
        unsigned v;
        do {
          v = __hip_atomic_load(&fA[t * 64 + lt], __ATOMIC_RELAXED, __HIP_MEMORY_SCOPE_AGENT);
          if (__all(v != 0u)) break;
          __builtin_amdgcn_s_sleep(1);
        } while (true);
      } else if (t > 0 && lt < 192) {
        unsigned v;
        do {
          v = __hip_atomic_load(&fB[(t - 1) * 128 + (lt - 64)], __ATOMIC_RELAXED, __HIP_MEMORY_SCOPE_AGENT);
          if (__all(v != 0u)) break;
          __builtin_amdgcn_s_sleep(1);
        } while (true);
      }
    }
    __syncthreads();                                   // B0: all deps confirmed

    // ---- S: bulk-stage h rows into LDS ----
    if (t == 0) {
#pragma unroll
      for (int j = 0; j < 8; ++j)
        *(float4*)&hx[0][sb * 520 + (j * 16 + sc) * 4] =
            *(const float4*)(h0g + sb * 512 + (j * 16 + sc) * 4);
    } else {
      bulk8_to_lds(ybuf + (size_t)(sb * T_ + t - 1) * 512, sc, &hx[0][sb * 520]);
    }
    if (isB)
      bulk8_to_lds(out0 + (size_t)(sb * T_ + t) * 512, sc, &hx[1][sb * 520]);
    __syncthreads();                                   // B1

    // ---- M: register-tiled matvec (4 batches x 6 rows / thread) ----
    const float* inb = (isB && rgrp >= 2) ? &hx[1][0] : &hx[0][0];
    float acc[6][4];
#pragma unroll
    for (int jr = 0; jr < 6; ++jr)
#pragma unroll
      for (int jb = 0; jb < 4; ++jb) acc[jr][jb] = 0.f;
#pragma unroll
    for (int i = 0; i < 8; ++i) {
      const int kb = kq * 4 + i * 64;
      float4 hv0 = *(const float4*)(inb + (bq * 4 + 0) * 520 + kb);
      float4 hv1 = *(const float4*)(inb + (bq * 4 + 1) * 520 + kb);
      float4 hv2 = *(const float4*)(inb + (bq * 4 + 2) * 520 + kb);
      float4 hv3 = *(const float4*)(inb + (bq * 4 + 3) * 520 + kb);
#pragma unroll
      for (int jr = 0; jr < 6; ++jr) {
        float4 wv = *(const float4*)(&Wl[rgrp * 6 + jr][kb]);
        acc[jr][0] += wv.x*hv0.x + wv.y*hv0.y + wv.z*hv0.z + wv.w*hv0.w;
        acc[jr][1] += wv.x*hv1.x + wv.y*hv1.y + wv.z*hv1.z + wv.w*hv1.w;
        acc[jr][2] += wv.x*hv2.x + wv.y*hv2.y + wv.z*hv2.z + wv.w*hv2.w;
        acc[jr][3] += wv.x*hv3.x + wv.y*hv3.y + wv.z*hv3.z + wv.w*hv3.w;
      }
    }
#pragma unroll
    for (int jr = 0; jr < 6; ++jr)
#pragma unroll
      for (int jb = 0; jb < 4; ++jb)
        ps[rgrp * 6 + jr][bq * 4 + jb][kq] = acc[jr][jb];
    __syncthreads();                                   // B2

    // ---- R: reduce + activations + state store ----
    if (lt < nred) {
      float ghr, ghz, ghn, ixr, ixz, ixn;
      if (!isB) {
        float s0 = 0.f, s1 = 0.f, s2 = 0.f;
#pragma unroll
        for (int q = 0; q < 16; ++q) {
          s0 += ps[rdl][rb][q];
          s1 += ps[8 + rdl][rb][q];
          s2 += ps[16 + rdl][rb][q];
        }
        ghr = s0 + bhr; ghz = s1 + bhz; ghn = s2 + bhn;
        const float* xrow = xg0 + (size_t)(rb * T_ + t) * 1536;
        ixr = xrow[rdg]; ixz = xrow[512 + rdg]; ixn = xrow[1024 + rdg];
      } else {
        float s0=0.f,s1=0.f,s2=0.f,s3=0.f,s4=0.f,s5=0.f;
#pragma unroll
        for (int q = 0; q < 16; ++q) {
          s0 += ps[rdl][rb][q];       s1 += ps[4 + rdl][rb][q];  s2 += ps[8 + rdl][rb][q];
          s3 += ps[12 + rdl][rb][q];  s4 += ps[16 + rdl][rb][q]; s5 += ps[20 + rdl][rb][q];
        }
        ghr = s0 + bhr; ghz = s1 + bhz; ghn = s2 + bhn;
        ixr = s3 + bir; ixz = s4 + biz; ixn = s5 + bin_;
      }
      float rr = 1.f / (1.f + expf(-(ixr + ghr)));
      float zz = 1.f / (1.f + expf(-(ixz + ghz)));
      float nn = tanhf(ixn + rr * ghn);
      float hp = hx[0][rb * 520 + rdg];
      float hnew = (1.f - zz) * nn + zz * hp;
      __hip_atomic_store(&ybuf[(size_t)(rb * T_ + t) * 512 + rdg], hnew,
                         __ATOMIC_RELAXED, __HIP_MEMORY_SCOPE_AGENT);
      if (t == T_ - 1) hn[(isB ? 8192 : 0) + rb * 512 + rdg] = hnew;
    }
    __syncthreads();                                   // B3: vmcnt(0) drain of stores
    if (lt == 0) {
      if (isB)
        __hip_atomic_store(&fB[t * 128 + wg], 1u, __ATOMIC_RELAXED, __HIP_MEMORY_SCOPE_AGENT);
      else
        __hip_atomic_store(&fA[t * 64 + wg], 1u, __ATOMIC_RELAXED, __HIP_MEMORY_SCOPE_AGENT);
    }
  }
}

// ---------------- attention: one WG per (b,t) row ----------------
__global__ __launch_bounds__(256) void k_attn(const float* __restrict__ y,
    const float* __restrict__ enc, float* __restrict__ aout)
{
  __shared__ float orow[512];
  __shared__ float wbuf[256];
  __shared__ float red[8];
  const int row = blockIdx.x;        // b*T+t
  const int b = row >> 7;
  const int lt = threadIdx.x;
  orow[lt]       = y[(size_t)row*512 + lt];
  orow[lt + 256] = y[(size_t)row*512 + lt + 256];
  __syncthreads();
  const float* er = enc + (size_t)(b*S_ + lt) * 512;
  float acc = 0.f;
  for (int k = 0; k < 512; k += 4) {
    float4 e = *(const float4*)(er + k);
    acc += orow[k]*e.x + orow[k+1]*e.y + orow[k+2]*e.z + orow[k+3]*e.w;
  }
  float m = acc;
#pragma unroll
  for (int off = 32; off > 0; off >>= 1) m = fmaxf(m, __shfl_down(m, off));
  if ((lt & 63) == 0) red[lt >> 6] = m;
  __syncthreads();
  float mx = fmaxf(fmaxf(red[0], red[1]), fmaxf(red[2], red[3]));
  float e = expf(acc - mx);
  wbuf[lt] = e;
  float s = e;
#pragma unroll
  for (int off = 32; off > 0; off >>= 1) s += __shfl_down(s, off);
  if ((lt & 63) == 0) red[4 + (lt >> 6)] = s;
  __syncthreads();
  const float inv = 1.f / (red[4] + red[5] + red[6] + red[7]);
  const int kk = lt * 2;
  float c0 = 0.f, c1 = 0.f;
  for (int s2 = 0; s2 < S_; ++s2) {
    float ws = wbuf[s2];
    float2 ev = *(const float2*)(enc + (size_t)(b*S_ + s2)*512 + kk);
    c0 += ws * ev.x; c1 += ws * ev.y;
  }
  aout[(size_t)row*512 + kk]     = orow[kk]     + c0 * inv;
  aout[(size_t)row*512 + kk + 1] = orow[kk + 1] + c1 * inv;
}

// ---------------- bf16 MFMA NT GEMM + bias for logits ----------------
__global__ __launch_bounds__(256) void k_gemm_bf16(const float* __restrict__ A,
    const float* __restrict__ Bm, const float* __restrict__ bias,
    float* __restrict__ C)
{
  __shared__ unsigned short As[128 * 40];
  __shared__ unsigned short Bs[128 * 40];
  const int tid = threadIdx.x;
  const int nbase = blockIdx.x * 128;
  const int mbase = blockIdx.y * 128;
  const int wv = tid >> 6;
  const int l  = tid & 63;
  const int wr = wv >> 1, wc = wv & 1;
  const int r = l & 15, q = l >> 4;

  float4v acc[4][4];
#pragma unroll
  for (int mi = 0; mi < 4; ++mi)
#pragma unroll
    for (int ni = 0; ni < 4; ++ni)
      acc[mi][ni] = (float4v){0.f, 0.f, 0.f, 0.f};

  for (int k0 = 0; k0 < 512; k0 += 32) {
    __syncthreads();
#pragma unroll
    for (int h = 0; h < 2; ++h) {
      const int c = tid + h * 256;
      const int row = c >> 2, cb = c & 3;
      const float* Ag = A + (size_t)(mbase + row) * 512 + k0 + cb * 8;
      float4 f0 = *(const float4*)(Ag);
      float4 f1 = *(const float4*)(Ag + 4);
      union { short8v v; __hip_bfloat162 h2[4]; } pa;
      pa.h2[0] = __float22bfloat162_rn({f0.x, f0.y});
      pa.h2[1] = __float22bfloat162_rn({f0.z, f0.w});
      pa.h2[2] = __float22bfloat162_rn({f1.x, f1.y});
      pa.h2[3] = __float22bfloat162_rn({f1.z, f1.w});
      *(short8v*)&As[row * 40 + cb * 8] = pa.v;
      const float* Bg = Bm + (size_t)(nbase + row) * 512 + k0 + cb * 8;
      float4 g0 = *(const float4*)(Bg);
      float4 g1 = *(const float4*)(Bg + 4);
      union { short8v v; __hip_bfloat162 h2[4]; } pb;
      pb.h2[0] = __float22bfloat162_rn({g0.x, g0.y});
      pb.h2[1] = __float22bfloat162_rn({g0.z, g0.w});
      pb.h2[2] = __float22bfloat162_rn({g1.x, g1.y});
      pb.h2[3] = __float22bfloat162_rn({g1.z, g1.w});
      *(short8v*)&Bs[row * 40 + cb * 8] = pb.v;
    }
    __syncthreads();

    short8v af[4], bf[4];
#pragma unroll
    for (int mi = 0; mi < 4; ++mi)
      af[mi] = *(short8v*)&As[(wr * 64 + mi * 16 + r) * 40 + q * 8];
#pragma unroll
    for (int ni = 0; ni < 4; ++ni)
      bf[ni] = *(short8v*)&Bs[(wc * 64 + ni * 16 + r) * 40 + q * 8];
#pragma unroll
    for (int mi = 0; mi < 4; ++mi)
#pragma unroll
      for (int ni = 0; ni < 4; ++ni)
        acc[mi][ni] = __builtin_amdgcn_mfma_f32_16x16x32_bf16(af[mi], bf[ni], acc[mi][ni], 0, 0, 0);
  }

  const int mg = mbase + wr * 64;
  const int ng = nbase + wc * 64;
#pragma unroll
  for (int ni = 0; ni < 4; ++ni) {
    const int col = ng + ni * 16 + r;
    const float bj = bias[col];
#pragma unroll
    for (int mi = 0; mi < 4; ++mi) {
      const int rowb = mg + mi * 16 + q * 4;
      float4v v = acc[mi][ni];
      C[(size_t)(rowb + 0) * V_ + col] = v[0] + bj;
      C[(size_t)(rowb + 1) * V_ + col] = v[1] + bj;
      C[(size_t)(rowb + 2) * V_ + col] = v[2] + bj;
      C[(size_t)(rowb + 3) * V_ + col] = v[3] + bj;
    }
  }
}

extern "C" void kernel_launch(void* const* d_in, const int* in_sizes, int n_in,
                              void* d_out, int out_size, void* d_ws, size_t ws_size,
                              hipStream_t stream)
{
  const int*   tgt    = (const int*)  d_in[0];
  const float* hidden = (const float*)d_in[1];
  const float* enc    = (const float*)d_in[2];
  const float* embed  = (const float*)d_in[3];
  const float* W_ih0  = (const float*)d_in[4];
  const float* W_hh0  = (const float*)d_in[5];
  const float* b_ih0  = (const float*)d_in[6];
  const float* b_hh0  = (const float*)d_in[7];
  const float* W_ih1  = (const float*)d_in[8];
  const float* W_hh1  = (const float*)d_in[9];
  const float* b_ih1  = (const float*)d_in[10];
  const float* b_hh1  = (const float*)d_in[11];
  const float* W_out  = (const float*)d_in[12];
  const float* b_out  = (const float*)d_in[13];
  float* out = (float*)d_out;

  float* ws   = (float*)d_ws;
  float* xbuf = ws;                          // 2048*512   (x, later attn_out)
  float* xg   = ws + 1048576;                // 2048*1536  (layer-0 input gates)
  float* out0 = xg + 3145728;                // 2048*512
  float* y1   = out0 + 1048576;              // 2048*512
  unsigned int* fA = (unsigned int*)(y1 + 1048576);   // 128*64 flags
  unsigned int* fB = fA + T_ * 64;                    // 128*128 flags

  const size_t logitsN = (size_t)(B_*T_) * V_;   // 65,536,000
  float* hn = out + logitsN;
  float* cn = hn + 16384;

  hipMemsetAsync(fA, 0, (size_t)(T_ * 64 + T_ * 128) * sizeof(unsigned int), stream);
  hipMemsetAsync(cn, 0, (size_t)16384 * sizeof(float), stream);   // cn = zeros

  k_gather<<<dim3(B_*T_), dim3(128), 0, stream>>>(tgt, embed, xbuf);
  k_gemm_nt_bias<<<dim3(1536/64, (B_*T_)/64), dim3(256), 0, stream>>>(xbuf, W_ih0, b_ih0, xg, 1536);
  k_gru2<<<dim3(256), dim3(256), 0, stream>>>(xg, W_hh0, b_hh0, W_ih1, b_ih1,
                                              W_hh1, b_hh1, hidden, out0, y1, hn, fA, fB);
  k_attn<<<dim3(B_*T_), dim3(256), 0, stream>>>(y1, enc, xbuf);
  k_gemm_bf16<<<dim3(V_/128, (B_*T_)/128), dim3(256), 0, stream>>>(xbuf, W_out, b_out, out);
}